// Round 1
// 913.585 us; speedup vs baseline: 1.0313x; 1.0313x over previous
//
#include <hip/hip_runtime.h>

// ---------------------------------------------------------------------------
// SublayerConnection: MHA + residual/LN + FF + residual/LN
// B=4 S=2048 D=1024 H=16 Dk=64 Dff=4096.
// Round 5: (1) T3-minimum double-buffered gemm_bb (DBUF template) for the
// grid-256 1-block/CU GEMMs (Wo, W2) — prefetch next K-tile via
// global_load_lds before MFMA, one barrier per K-step. (2) mask all-ones
// fast path (67MB scan once, attn skips 512 mask loads/thread). (3) attn:
// Q in registers (LDS 59->51KB, 3 blocks/CU), K staged via global_load_lds,
// V^T staging vectorized (b64 writes), batches merged via grid.y.
// ---------------------------------------------------------------------------

#define DM   1024
#define DFF  4096
#define SEQ  2048

typedef unsigned short u16;
typedef short          sx8  __attribute__((ext_vector_type(8)));
typedef unsigned short ushx8 __attribute__((ext_vector_type(8)));
typedef unsigned short ushx4 __attribute__((ext_vector_type(4)));
typedef float          fx4  __attribute__((ext_vector_type(4)));

__device__ __forceinline__ void async16(const void* g, void* l) {
  __builtin_amdgcn_global_load_lds((__attribute__((address_space(1))) void*)g,
                                   (__attribute__((address_space(3))) void*)l,
                                   16, 0, 0);
}
__device__ __forceinline__ float b2f(u16 u) {
  union { unsigned int i; float f; } v; v.i = ((unsigned int)u) << 16; return v.f;
}
__device__ __forceinline__ u16 f2b(float f) {
  union { float f; unsigned int i; } v; v.f = f;
  unsigned int r = v.i + 0x7fffu + ((v.i >> 16) & 1u);
  return (u16)(r >> 16);
}
__device__ __forceinline__ ushx8 ld8(const void* p, long idx, bool f32) {
  if (f32) {
    const float* s = (const float*)p + idx;
    fx4 a = *(const fx4*)s, b = *(const fx4*)(s + 4);
    ushx8 r;
    r[0] = f2b(a[0]); r[1] = f2b(a[1]); r[2] = f2b(a[2]); r[3] = f2b(a[3]);
    r[4] = f2b(b[0]); r[5] = f2b(b[1]); r[6] = f2b(b[2]); r[7] = f2b(b[3]);
    return r;
  }
  return *(const ushx8*)((const u16*)p + idx);
}
__device__ __forceinline__ void ld4f(const void* p, long idx, bool f32, float* o) {
  if (f32) {
    fx4 a = *(const fx4*)((const float*)p + idx);
    o[0] = a[0]; o[1] = a[1]; o[2] = a[2]; o[3] = a[3];
  } else {
    ushx4 a = *(const ushx4*)((const u16*)p + idx);
    o[0] = b2f(a[0]); o[1] = b2f(a[1]); o[2] = b2f(a[2]); o[3] = b2f(a[3]);
  }
}

// ---------------------------------------------------------------------------
__global__ void detect_kernel(const void* q, int* flags) {
  int lane = threadIdx.x;
  u16 v = ((const u16*)q)[lane << 1];
  int e = (v >> 7) & 0xff;
  int pl = (e >= 0x60 && e <= 0x8c) ? 1 : 0;
  unsigned long long m = __ballot(pl);
  if (lane == 0) { flags[0] = (__popcll(m) >= 40) ? 0 : 1; flags[1] = 0; flags[2] = 1; }
}

// Scan mask for any zero; flags[2] stays 1 iff every element nonzero.
__global__ __launch_bounds__(256)
void mask_scan(const int* __restrict__ m, int* flags) {
  long i = (((long)blockIdx.x << 8) + threadIdx.x) << 3;
  const int4 a = *(const int4*)(m + i);
  const int4 b = *(const int4*)(m + i + 4);
  bool ok = a.x && a.y && a.z && a.w && b.x && b.y && b.z && b.w;
  if (!__all(ok)) { if ((threadIdx.x & 63) == 0) flags[2] = 0; }
}

// Pack Wq/Wk/Wv -> Wqkv [3*1024,1024] bf16 and Wo -> bf16.
__global__ __launch_bounds__(256)
void pack_w(const void* Wq, const void* Wk, const void* Wv, const void* Wo,
            u16* Wqkv, u16* Wo_bf, const int* f_p) {
  const bool f = (*f_p != 0);
  long i = (((long)blockIdx.x << 8) + threadIdx.x) << 3;
  const long QKVN = (long)3 * DM * DM;
  if (i < QKVN) {
    int row = (int)(i >> 10);
    const void* src = (row < DM) ? Wq : (row < 2 * DM ? Wk : Wv);
    long s = ((long)(row & (DM - 1)) << 10) + (i & 1023);
    *(ushx8*)(Wqkv + i) = ld8(src, s, f);
  } else {
    long j = i - QKVN;
    *(ushx8*)(Wo_bf + j) = ld8(Wo, j, f);
  }
}

// Convert q/k/v chunk to bf16; grid.y selects source, dst stride n.
__global__ __launch_bounds__(256)
void conv_bf3(const void* q, const void* k, const void* v, long off,
              u16* dst, long n, const int* f_p) {
  const bool f = (*f_p != 0);
  const void* src = (blockIdx.y == 0) ? q : (blockIdx.y == 1 ? k : v);
  long i = (((long)blockIdx.x << 8) + threadIdx.x) << 3;
  if (i < n) *(ushx8*)(dst + (long)blockIdx.y * n + i) = ld8(src, off + i, f);
}

// ---------------------------------------------------------------------------
// Pure-bf16 NT GEMM with global_load_lds(16B) staging. C=A@B^T (+bias)(+relu).
// grid.y = z selects (A,B,C) via element strides az/bz/cz. C row stride ldc.
// DBUF: double-buffered LDS, prefetch-before-compute, one barrier per K-step
// (for grid-limited 1-block/CU dispatches: Wo, W2).
// ---------------------------------------------------------------------------
template<bool RELU, bool BIAS, bool DBUF>
__global__ __launch_bounds__(256)
void gemm_bb(const u16* __restrict__ A, long az, const u16* __restrict__ B, long bz,
             const void* __restrict__ bias, u16* __restrict__ C, long cz,
             int M, int N, int K, int ldc, const int* biasf_p) {
  __shared__ __align__(16) u16 sA[(DBUF ? 2 : 1) * 128 * 64];
  __shared__ __align__(16) u16 sB[(DBUF ? 2 : 1) * 128 * 64];
  const int z = blockIdx.y;
  A += (long)z * az; B += (long)z * bz; C += (long)z * cz;
  const bool biasf = BIAS && (*biasf_p != 0);
  const int t = threadIdx.x;
  const int lane = t & 63, w = t >> 6;
  const int lm = lane & 15, lg = lane >> 4;
  const int ntil = N >> 7;
  const int m0 = (blockIdx.x / ntil) << 7;
  const int n0 = (blockIdx.x % ntil) << 7;
  const int wm = (w & 1) << 6, wn = (w >> 1) << 6;

  fx4 acc[4][4];
#pragma unroll
  for (int i = 0; i < 4; ++i)
#pragma unroll
    for (int j = 0; j < 4; ++j) acc[i][j] = (fx4){0.f, 0.f, 0.f, 0.f};

  auto stage = [&](int buf, int kt) {
    const int so = DBUF ? (buf << 13) : 0;
#pragma unroll
    for (int it = 0; it < 4; ++it) {
      int ci = (it << 8) + t;
      int r = ci >> 3, cs = (ci & 7) ^ (r & 7);
      async16(&A[(size_t)(m0 + r) * K + kt + (cs << 3)], &sA[so + (ci << 3)]);
    }
#pragma unroll
    for (int it = 0; it < 4; ++it) {
      int ci = (it << 8) + t;
      int r = ci >> 3, cs = (ci & 7) ^ (r & 7);
      async16(&B[(size_t)(n0 + r) * K + kt + (cs << 3)], &sB[so + (ci << 3)]);
    }
  };

  if (DBUF) { stage(0, 0); __syncthreads(); }
  int cur = 0;
  for (int kt = 0; kt < K; kt += 64) {
    if (DBUF) {
      if (kt + 64 < K) stage(cur ^ 1, kt + 64);   // prefetch overlaps MFMA below
    } else {
      __syncthreads();
      stage(0, kt);
      __syncthreads();
    }
    const int so = DBUF ? (cur << 13) : 0;
#pragma unroll
    for (int s = 0; s < 2; ++s) {
      const int g = (s << 2) + lg;
      sx8 afr[4], bfr[4];
#pragma unroll
      for (int i = 0; i < 4; ++i) {
        int ra = wm + (i << 4) + lm;
        afr[i] = *(const sx8*)&sA[so + ra * 64 + ((g ^ (ra & 7)) << 3)];
        int rb = wn + (i << 4) + lm;
        bfr[i] = *(const sx8*)&sB[so + rb * 64 + ((g ^ (rb & 7)) << 3)];
      }
#pragma unroll
      for (int i = 0; i < 4; ++i)
#pragma unroll
        for (int j = 0; j < 4; ++j)
          acc[i][j] = __builtin_amdgcn_mfma_f32_16x16x32_bf16(afr[i], bfr[j], acc[i][j], 0, 0, 0);
    }
    if (DBUF && kt + 64 < K) __syncthreads();   // drains prefetch into buf^1
    cur ^= 1;
  }

#pragma unroll
  for (int j = 0; j < 4; ++j) {
    const int col = n0 + wn + (j << 4) + lm;
    float bv = 0.f;
    if (BIAS) bv = biasf ? ((const float*)bias)[col] : b2f(((const u16*)bias)[col]);
#pragma unroll
    for (int i = 0; i < 4; ++i) {
      const int row0 = m0 + wm + (i << 4) + (lg << 2);
#pragma unroll
      for (int r = 0; r < 4; ++r) {
        float v = acc[i][j][r] + bv;
        if (RELU) v = fmaxf(v, 0.f);
        C[(size_t)(row0 + r) * ldc + col] = f2b(v);
      }
    }
  }
}

// ---------------------------------------------------------------------------
// Flag-dtype NT GEMM (legacy path, proven in round 3).
// ---------------------------------------------------------------------------
template<bool RELU, bool BIAS>
__global__ __launch_bounds__(256)
void gemm_nt(const void* __restrict__ A, long aoff, const void* __restrict__ Bm,
             const void* __restrict__ bias, u16* __restrict__ C,
             int M, int N, int K,
             const int* af_p, const int* bf_p, const int* biasf_p) {
  __shared__ __align__(16) u16 sA[128 * 64];
  __shared__ __align__(16) u16 sB[128 * 64];
  const bool af = (*af_p != 0), bfl = (*bf_p != 0), biasf = (*biasf_p != 0);
  const int t = threadIdx.x;
  const int lane = t & 63, w = t >> 6;
  const int lm = lane & 15, lg = lane >> 4;
  const int ntil = N >> 7;
  const int m0 = (blockIdx.x / ntil) << 7;
  const int n0 = (blockIdx.x % ntil) << 7;
  const int wm = (w & 1) << 6, wn = (w >> 1) << 6;

  fx4 acc[4][4];
#pragma unroll
  for (int i = 0; i < 4; ++i)
#pragma unroll
    for (int j = 0; j < 4; ++j) acc[i][j] = (fx4){0.f, 0.f, 0.f, 0.f};

  for (int kt = 0; kt < K; kt += 64) {
    __syncthreads();
#pragma unroll
    for (int it = 0; it < 4; ++it) {
      int ci = (it << 8) + t;
      int r = ci >> 3, cs = (ci & 7) ^ (r & 7);
      ushx8 va = ld8(A, aoff + (long)(m0 + r) * K + kt + (cs << 3), af);
      *(ushx8*)&sA[ci << 3] = va;
      ushx8 vb = ld8(Bm, (long)(n0 + r) * K + kt + (cs << 3), bfl);
      *(ushx8*)&sB[ci << 3] = vb;
    }
    __syncthreads();
#pragma unroll
    for (int s = 0; s < 2; ++s) {
      const int g = (s << 2) + lg;
      sx8 afr[4], bfr[4];
#pragma unroll
      for (int i = 0; i < 4; ++i) {
        int ra = wm + (i << 4) + lm;
        afr[i] = *(const sx8*)&sA[ra * 64 + ((g ^ (ra & 7)) << 3)];
        int rb = wn + (i << 4) + lm;
        bfr[i] = *(const sx8*)&sB[rb * 64 + ((g ^ (rb & 7)) << 3)];
      }
#pragma unroll
      for (int i = 0; i < 4; ++i)
#pragma unroll
        for (int j = 0; j < 4; ++j)
          acc[i][j] = __builtin_amdgcn_mfma_f32_16x16x32_bf16(afr[i], bfr[j], acc[i][j], 0, 0, 0);
    }
  }

#pragma unroll
  for (int j = 0; j < 4; ++j) {
    const int col = n0 + wn + (j << 4) + lm;
    float bv = 0.f;
    if (BIAS) bv = biasf ? ((const float*)bias)[col] : b2f(((const u16*)bias)[col]);
#pragma unroll
    for (int i = 0; i < 4; ++i) {
      const int row0 = m0 + wm + (i << 4) + (lg << 2);
#pragma unroll
      for (int r = 0; r < 4; ++r) {
        float v = acc[i][j][r] + bv;
        if (RELU) v = fmaxf(v, 0.f);
        C[(size_t)(row0 + r) * N + col] = f2b(v);
      }
    }
  }
}

// ---------------------------------------------------------------------------
__global__ __launch_bounds__(256)
void transpose_any(const void* __restrict__ in, u16* __restrict__ out,
                   int R, int C, const int* f_p) {
  __shared__ u16 tile[64][68];
  const bool f = (*f_p != 0);
  const int r0 = blockIdx.y << 6, c0 = blockIdx.x << 6;
  const int t = threadIdx.x;
#pragma unroll
  for (int it = 0; it < 4; ++it) {
    int j = (it << 8) + t;
    int rr = j >> 4, cc4 = (j & 15) << 2;
    float v[4];
    ld4f(in, (long)(r0 + rr) * C + c0 + cc4, f, v);
#pragma unroll
    for (int q = 0; q < 4; ++q) tile[rr][cc4 + q] = f2b(v[q]);
  }
  __syncthreads();
#pragma unroll
  for (int it = 0; it < 4; ++it) {
    int j = (it << 8) + t;
    int cc = j >> 4, rr4 = (j & 15) << 2;
    ushx4 v;
    v[0] = tile[rr4 + 0][cc]; v[1] = tile[rr4 + 1][cc];
    v[2] = tile[rr4 + 2][cc]; v[3] = tile[rr4 + 3][cc];
    *(ushx4*)&out[(size_t)(c0 + cc) * R + r0 + rr4] = v;
  }
}

// ---------------------------------------------------------------------------
// Flash attention. grid.x = (h<<5)|qblock; grid.y = batch within this launch.
// Batch strides: qkv rows SEQ*lds_, mask SEQ*SEQ, ctx SEQ*DM.
// Q held in registers; K staged via global_load_lds; V^T staged with b64
// vectorized LDS writes. mflag!=0 => mask is all-ones, skip mask loads.
// ---------------------------------------------------------------------------
__global__ __launch_bounds__(256, 3)
void attn_kernel(const u16* __restrict__ qp, const u16* __restrict__ kp,
                 const u16* __restrict__ vp, int lds_,
                 const int* __restrict__ mask, u16* __restrict__ ctx,
                 const int* __restrict__ mflag) {
  __shared__ __align__(16) u16 sK[128 * 64];
  __shared__ __align__(16) u16 sVt[64 * 136];
  __shared__ __align__(16) u16 sP[4][16 * 136];

  const bool nomask = (*mflag != 0);
  const long boff = (long)blockIdx.y * SEQ * (long)lds_;
  qp += boff; kp += boff; vp += boff;
  mask += (size_t)blockIdx.y * SEQ * SEQ;
  ctx += (size_t)blockIdx.y * SEQ * DM;

  const int id = blockIdx.x;
  const int q0 = (id & 31) << 6;
  const int h  = id >> 5;
  const int t = threadIdx.x, lane = t & 63, w = t >> 6;
  const int hoff = h << 6;
  const int lm = lane & 15, lg = lane >> 4;

  // Q fragments in registers (per-wave 16 rows, 2 k-octets per lane)
  sx8 aq[2];
  {
    const int rowq = q0 + (w << 4) + lm;
#pragma unroll
    for (int s = 0; s < 2; ++s) {
      ushx8 v = *(const ushx8*)&qp[(size_t)rowq * lds_ + hoff + ((((s << 2) + lg)) << 3)];
#pragma unroll
      for (int j = 0; j < 8; ++j) aq[s][j] = (short)v[j];
    }
  }

  fx4 o[4];
  float m_prev[4], lsum[4];
#pragma unroll
  for (int i = 0; i < 4; ++i) { o[i] = (fx4){0.f, 0.f, 0.f, 0.f}; m_prev[i] = -1e30f; lsum[i] = 0.f; }

  for (int kt = 0; kt < 16; ++kt) {
    const int k0 = kt << 7;
    __syncthreads();
    // K -> sK (async, swizzled source, linear LDS)
#pragma unroll
    for (int it = 0; it < 4; ++it) {
      int ci = (it << 8) + t;
      int r = ci >> 3, cs = (ci & 7) ^ (r & 7);
      async16(&kp[(size_t)(k0 + r) * lds_ + hoff + (cs << 3)], &sK[ci << 3]);
    }
    // V -> sVt transposed: thread owns 4 keys x 8 d; 8x ds_write_b64
    {
      const int kq = (t & 31) << 2, dg = (t >> 5) << 3;
      ushx8 vv[4];
#pragma unroll
      for (int i = 0; i < 4; ++i)
        vv[i] = *(const ushx8*)&vp[(size_t)(k0 + kq + i) * lds_ + hoff + dg];
#pragma unroll
      for (int j = 0; j < 8; ++j) {
        ushx4 wv;
        wv[0] = vv[0][j]; wv[1] = vv[1][j]; wv[2] = vv[2][j]; wv[3] = vv[3][j];
        *(ushx4*)&sVt[(dg + j) * 136 + kq] = wv;
      }
    }
    __syncthreads();

    fx4 sc[8];
#pragma unroll
    for (int nt = 0; nt < 8; ++nt) sc[nt] = (fx4){0.f, 0.f, 0.f, 0.f};
#pragma unroll
    for (int s = 0; s < 2; ++s) {
      const int g = (s << 2) + lg;
#pragma unroll
      for (int nt = 0; nt < 8; ++nt) {
        int rk = (nt << 4) + lm;
        sx8 bk = *(const sx8*)&sK[rk * 64 + ((g ^ (rk & 7)) << 3)];
        sc[nt] = __builtin_amdgcn_mfma_f32_16x16x32_bf16(aq[s], bk, sc[nt], 0, 0, 0);
      }
    }

    float pmat[8][4];
    float tmax[4] = {-1e30f, -1e30f, -1e30f, -1e30f};
#pragma unroll
    for (int nt = 0; nt < 8; ++nt) {
      const int col = k0 + (nt << 4) + lm;
#pragma unroll
      for (int r = 0; r < 4; ++r) {
        float v = sc[nt][r] * 0.125f;
        if (!nomask) {
          const int rowg = q0 + (w << 4) + (lg << 2) + r;
          if (mask[((size_t)rowg << 11) + col] == 0) v = -1e9f;
        }
        pmat[nt][r] = v;
        tmax[r] = fmaxf(tmax[r], v);
      }
    }
#pragma unroll
    for (int r = 0; r < 4; ++r)
#pragma unroll
      for (int off = 1; off < 16; off <<= 1)
        tmax[r] = fmaxf(tmax[r], __shfl_xor(tmax[r], off));

    float alpha[4], rsum[4] = {0.f, 0.f, 0.f, 0.f};
#pragma unroll
    for (int r = 0; r < 4; ++r) {
      float mn = fmaxf(m_prev[r], tmax[r]);
      alpha[r] = __expf(m_prev[r] - mn);
      m_prev[r] = mn;
    }
#pragma unroll
    for (int nt = 0; nt < 8; ++nt)
#pragma unroll
      for (int r = 0; r < 4; ++r) {
        float pv = __expf(pmat[nt][r] - m_prev[r]);
        pmat[nt][r] = pv;
        rsum[r] += pv;
      }
#pragma unroll
    for (int r = 0; r < 4; ++r) {
#pragma unroll
      for (int off = 1; off < 16; off <<= 1)
        rsum[r] += __shfl_xor(rsum[r], off);
      lsum[r] = lsum[r] * alpha[r] + rsum[r];
    }
#pragma unroll
    for (int ot = 0; ot < 4; ++ot)
#pragma unroll
      for (int r = 0; r < 4; ++r)
        o[ot][r] *= alpha[r];

    u16* pw = &sP[w][0];
#pragma unroll
    for (int nt = 0; nt < 8; ++nt)
#pragma unroll
      for (int r = 0; r < 4; ++r)
        pw[((lg << 2) + r) * 136 + (nt << 4) + lm] = f2b(pmat[nt][r]);

#pragma unroll
    for (int ks = 0; ks < 4; ++ks) {
      sx8 ap = *(const sx8*)&pw[lm * 136 + (ks << 5) + (lg << 3)];
#pragma unroll
      for (int ot = 0; ot < 4; ++ot) {
        int d = (ot << 4) + lm;
        sx8 bv = *(const sx8*)&sVt[d * 136 + (ks << 5) + (lg << 3)];
        o[ot] = __builtin_amdgcn_mfma_f32_16x16x32_bf16(ap, bv, o[ot], 0, 0, 0);
      }
    }
  }

  float inv[4];
#pragma unroll
  for (int r = 0; r < 4; ++r) inv[r] = (lsum[r] > 0.f) ? 1.f / lsum[r] : 0.f;
#pragma unroll
  for (int ot = 0; ot < 4; ++ot)
#pragma unroll
    for (int r = 0; r < 4; ++r) {
      const int rowg = q0 + (w << 4) + (lg << 2) + r;
      const int col = hoff + (ot << 4) + lm;
      ctx[((size_t)rowg << 10) + col] = f2b(o[ot][r] * inv[r]);
    }
}

// ---------------------------------------------------------------------------
__global__ __launch_bounds__(256)
void ln_dual(const u16* __restrict__ a, const void* __restrict__ res, long roff,
             const void* __restrict__ g1, const void* __restrict__ b1,
             const void* __restrict__ gf, const void* __restrict__ bf,
             u16* __restrict__ xo, u16* __restrict__ xlo, const int* f_p) {
  __shared__ float red[8];
  const bool f = (*f_p != 0);
  const int row = blockIdx.x, t = threadIdx.x;
  const int lane = t & 63, w = t >> 6;
  const size_t base = (size_t)row << 10;
  const int c = t << 2;

  ushx4 a4 = *(const ushx4*)(a + base + c);
  float rv[4];
  ld4f(res, roff + (long)base + c, f, rv);
  float v[4], s = 0.f, ss = 0.f;
#pragma unroll
  for (int j = 0; j < 4; ++j) { v[j] = b2f(a4[j]) + rv[j]; s += v[j]; ss += v[j] * v[j]; }
#pragma unroll
  for (int off = 32; off > 0; off >>= 1) { s += __shfl_xor(s, off); ss += __shfl_xor(ss, off); }
  if (lane == 0) { red[w] = s; red[4 + w] = ss; }
  __syncthreads();
  s = red[0] + red[1] + red[2] + red[3];
  ss = red[4] + red[5] + red[6] + red[7];
  float mu = s * (1.f / 1024.f);
  float rstd = rsqrtf(fmaxf(ss * (1.f / 1024.f) - mu * mu, 0.f) + 1e-5f);

  float g4[4], b4[4];
  ld4f(g1, c, f, g4); ld4f(b1, c, f, b4);
  float x[4], s2 = 0.f, ss2 = 0.f;
  ushx4 xo4;
#pragma unroll
  for (int j = 0; j < 4; ++j) {
    x[j] = (v[j] - mu) * rstd * g4[j] + b4[j];
    xo4[j] = f2b(x[j]);
    s2 += x[j]; ss2 += x[j] * x[j];
  }
  *(ushx4*)(xo + base + c) = xo4;
#pragma unroll
  for (int off = 32; off > 0; off >>= 1) { s2 += __shfl_xor(s2, off); ss2 += __shfl_xor(ss2, off); }
  __syncthreads();
  if (lane == 0) { red[w] = s2; red[4 + w] = ss2; }
  __syncthreads();
  s2 = red[0] + red[1] + red[2] + red[3];
  ss2 = red[4] + red[5] + red[6] + red[7];
  float mu2 = s2 * (1.f / 1024.f);
  float rstd2 = rsqrtf(fmaxf(ss2 * (1.f / 1024.f) - mu2 * mu2, 0.f) + 1e-5f);

  ld4f(gf, c, f, g4); ld4f(bf, c, f, b4);
  ushx4 xl4;
#pragma unroll
  for (int j = 0; j < 4; ++j)
    xl4[j] = f2b((x[j] - mu2) * rstd2 * g4[j] + b4[j]);
  *(ushx4*)(xlo + base + c) = xl4;
}

// ---------------------------------------------------------------------------
__global__ __launch_bounds__(256)
void ln_final(const u16* __restrict__ a, const u16* __restrict__ resx,
              const void* __restrict__ g, const void* __restrict__ bb,
              void* __restrict__ out, long ooff, const int* f_p) {
  __shared__ float red[8];
  const bool f = (*f_p != 0);
  const int row = blockIdx.x, t = threadIdx.x;
  const int lane = t & 63, w = t >> 6;
  const size_t base = (size_t)row << 10;
  const int c = t << 2;

  ushx4 a4 = *(const ushx4*)(a + base + c);
  ushx4 r4 = *(const ushx4*)(resx + base + c);
  float v[4], s = 0.f, ss = 0.f;
#pragma unroll
  for (int j = 0; j < 4; ++j) { v[j] = b2f(a4[j]) + b2f(r4[j]); s += v[j]; ss += v[j] * v[j]; }
#pragma unroll
  for (int off = 32; off > 0; off >>= 1) { s += __shfl_xor(s, off); ss += __shfl_xor(ss, off); }
  if (lane == 0) { red[w] = s; red[4 + w] = ss; }
  __syncthreads();
  s = red[0] + red[1] + red[2] + red[3];
  ss = red[4] + red[5] + red[6] + red[7];
  float mu = s * (1.f / 1024.f);
  float rstd = rsqrtf(fmaxf(ss * (1.f / 1024.f) - mu * mu, 0.f) + 1e-5f);

  float g4[4], b4[4];
  ld4f(g, c, f, g4); ld4f(bb, c, f, b4);
  if (f) {
    fx4 o4;
#pragma unroll
    for (int j = 0; j < 4; ++j) o4[j] = (v[j] - mu) * rstd * g4[j] + b4[j];
    *(fx4*)((float*)out + ooff + base + c) = o4;
  } else {
    ushx4 o4;
#pragma unroll
    for (int j = 0; j < 4; ++j) o4[j] = f2b((v[j] - mu) * rstd * g4[j] + b4[j]);
    *(ushx4*)((u16*)out + ooff + base + c) = o4;
  }
}

// ---------------------------------------------------------------------------
extern "C" void kernel_launch(void* const* d_in, const int* in_sizes, int n_in,
                              void* d_out, int out_size, void* d_ws, size_t ws_size,
                              hipStream_t stream) {
  (void)in_sizes; (void)n_in; (void)out_size;
  const void* query = d_in[0];
  const void* keyi  = d_in[1];
  const void* value = d_in[2];
  const int*  mask  = (const int*)d_in[3];
  const void* Wq = d_in[4];
  const void* Wk = d_in[5];
  const void* Wv = d_in[6];
  const void* Wo = d_in[7];
  const void* bo = d_in[8];
  const void* g1 = d_in[9];
  const void* b1 = d_in[10];
  const void* g2 = d_in[11];
  const void* b2 = d_in[12];
  const void* gff = d_in[13];
  const void* bff = d_in[14];
  const void* W1 = d_in[15];
  const void* bf1 = d_in[16];
  const void* W2 = d_in[17];
  const void* bf2 = d_in[18];

  char* p = (char*)d_ws;
  int* flags = (int*)p;
  const int* F = flags;
  const int* Z = flags + 1;
  const int* M = flags + 2;
  dim3 blk(256);

  // footprint(CH) = 4096 + 24MiB (packed weights) + 7*CH*2048 bytes
  const size_t FIXED = 4096 + ((size_t)24 << 20);
  const size_t needA = FIXED + (size_t)4096 * 14336;   // ~80.0 MB
  const size_t needB = FIXED + (size_t)2048 * 14336;   // ~52.0 MB

  if (ws_size >= needB) {
    // ------------------------- NEW PATH -------------------------
    const int CH = (ws_size >= needA) ? 4096 : 2048;
    const int nch = 8192 / CH;

    u16* Wqkv  = (u16*)(p + 4096);                       // [3*1024,1024]
    u16* Wo_bf = Wqkv + (size_t)3 * DM * DM;             // [1024,1024]
    u16* W1T   = Wo_bf + (size_t)DM * DM;                // [4096,1024]
    u16* W2T   = W1T + (size_t)DFF * DM;                 // [1024,4096]
    u16* D0    = W2T + (size_t)DM * DFF;                 // in_bf / h
    u16* D1    = D0 + (size_t)3 * CH * DM;               // qkv / ao,x,xln
    u16* D2    = D1 + (size_t)3 * CH * DM;               // ctx / ff
    u16* qb = D0;
    u16* qkv = D1;
    u16* ao = D1, *x = D1 + (size_t)CH * DM, *xln = D1 + (size_t)2 * CH * DM;
    u16* h = D0;                                         // CH*4096 elems
    u16* ctx = D2, *ff = D2;

    detect_kernel<<<1, 64, 0, stream>>>(query, flags);
    mask_scan<<<dim3(8192), blk, 0, stream>>>(mask, flags);
    pack_w<<<dim3(2048), blk, 0, stream>>>(Wq, Wk, Wv, Wo, Wqkv, Wo_bf, F);
    transpose_any<<<dim3(DFF / 64, DM / 64), blk, 0, stream>>>(W1, W1T, DM, DFF, F);
    transpose_any<<<dim3(DM / 64, DFF / 64), blk, 0, stream>>>(W2, W2T, DFF, DM, F);

    for (int c = 0; c < nch; ++c) {
      const long off = (long)c * CH * DM;
      const long n = (long)CH * DM;
      conv_bf3<<<dim3((int)(n >> 11), 3), blk, 0, stream>>>(query, keyi, value, off, qb, n, F);

      // q/k/v projections co-dispatched: z in {0,1,2}
      gemm_bb<false, false, false><<<dim3((CH / 128) * 8, 3), blk, 0, stream>>>(
          qb, (long)CH * DM, Wqkv, (long)DM * DM, nullptr,
          qkv, 1024L, CH, DM, DM, 3072, Z);

      const int bpc = CH / SEQ, b0 = c * bpc;
      attn_kernel<<<dim3(512, bpc), blk, 0, stream>>>(
          qkv, qkv + 1024, qkv + 2048, 3072,
          mask + (size_t)b0 * SEQ * SEQ, ctx, M);

      gemm_bb<false, true, true><<<dim3((CH / 128) * 8, 1), blk, 0, stream>>>(
          ctx, 0, Wo_bf, 0, bo, ao, 0, CH, DM, DM, DM, F);

      ln_dual<<<dim3(CH), blk, 0, stream>>>(ao, query, off, g1, b1, gff, bff, x, xln, F);

      gemm_bb<true, true, false><<<dim3((CH / 128) * 32, 1), blk, 0, stream>>>(
          xln, 0, W1T, 0, bf1, h, 0, CH, DFF, DM, DFF, F);
      gemm_bb<false, true, true><<<dim3((CH / 128) * 8, 1), blk, 0, stream>>>(
          h, 0, W2T, 0, bf2, ff, 0, CH, DM, DFF, DM, F);

      ln_final<<<dim3(CH), blk, 0, stream>>>(ff, x, g2, b2, d_out, off, F);
    }
  } else {
    // ------------------------- LEGACY PATH (round-3 proven) -------------------------
    const int CH = 2048, FH = 1024;
    const int nch = 8192 / CH;
    const size_t h0 = 4096;
    u16* W1T = (u16*)(p + h0);
    u16* W2T = W1T + (size_t)DFF * DM;
    u16* hb  = (u16*)(p + h0 + ((size_t)16 << 20));
    const size_t HB = (size_t)FH * DFF * 2;
    u16* r0 = (u16*)(p + h0 + ((size_t)16 << 20) + HB);
    const size_t CE = (size_t)CH * DM;
    u16* qp = r0;
    u16* kp = qp + CE;
    u16* vp = kp + CE;
    u16* ctxb = vp + CE;
    u16* x = qp; u16* xln = kp; u16* ao = vp; u16* ff = ctxb;

    detect_kernel<<<1, 64, 0, stream>>>(query, flags);
    mask_scan<<<dim3(8192), blk, 0, stream>>>(mask, flags);
    transpose_any<<<dim3(DFF / 64, DM / 64), blk, 0, stream>>>(W1, W1T, DM, DFF, F);
    transpose_any<<<dim3(DM / 64, DFF / 64), blk, 0, stream>>>(W2, W2T, DFF, DM, F);

    for (int c = 0; c < nch; ++c) {
      const long off = (long)c * CH * DM;
      dim3 gq((CH / 128) * (DM / 128));

      gemm_nt<false, false><<<gq, blk, 0, stream>>>(query, off, Wq, Wq, qp, CH, DM, DM, F, F, Z);
      gemm_nt<false, false><<<gq, blk, 0, stream>>>(keyi,  off, Wk, Wk, kp, CH, DM, DM, F, F, Z);
      gemm_nt<false, false><<<gq, blk, 0, stream>>>(value, off, Wv, Wv, vp, CH, DM, DM, F, F, Z);

      const int bpc = CH / SEQ, b0 = c * bpc;
      for (int bl = 0; bl < bpc; ++bl) {
        const size_t lo = (size_t)bl * SEQ * DM;
        attn_kernel<<<dim3(512, 1), blk, 0, stream>>>(
            qp + lo, kp + lo, vp + lo, 1024,
            mask + (size_t)(b0 + bl) * SEQ * SEQ, ctxb + lo, M);
      }

      gemm_nt<false, true><<<gq, blk, 0, stream>>>(ctxb, 0, Wo, bo, ao, CH, DM, DM, Z, F, F);

      ln_dual<<<dim3(CH), blk, 0, stream>>>(ao, query, off, g1, b1, gff, bff, x, xln, F);

      for (int qs = 0; qs < CH / FH; ++qs) {
        const long so = (long)qs * FH * DM;
        gemm_nt<true, true><<<dim3((FH / 128) * (DFF / 128)), blk, 0, stream>>>(
            xln + so, 0, W1T, bf1, hb, FH, DFF, DM, Z, Z, F);
        gemm_nt<false, true><<<dim3((FH / 128) * (DM / 128)), blk, 0, stream>>>(
            hb, 0, W2T, bf2, ff + so, FH, DM, DFF, Z, Z, F);
      }

      ln_final<<<dim3(CH), blk, 0, stream>>>(ff, x, g2, b2, d_out, off, F);
    }
  }
}

// Round 2
// 830.777 us; speedup vs baseline: 1.1340x; 1.0997x over previous
//
#include <hip/hip_runtime.h>

// ---------------------------------------------------------------------------
// SublayerConnection: MHA + residual/LN + FF + residual/LN
// B=4 S=2048 D=1024 H=16 Dk=64 Dff=4096.
// Round 6: (1) attn rewritten: swapped QK^T (mfma(K,Q)) puts each P-row in
// one lane -> softmax per-lane + 2 shfls, P->bf16 via v_cvt_pk_bf16_f32,
// PV A-fragments via register shuffles; sP eliminated (LDS 51->34KB, 4
// blocks/CU); log2-domain softmax w/ defer-max; v_perm V packing; XCD
// swizzle. (2) gemm_bb DBUF: raw s_barrier + counted s_waitcnt vmcnt(8)
// so prefetch truly spans the barrier (Wo, W2 at 1 wave/SIMD).
// ---------------------------------------------------------------------------

#define DM   1024
#define DFF  4096
#define SEQ  2048

typedef unsigned short u16;
typedef short          sx8  __attribute__((ext_vector_type(8)));
typedef unsigned short ushx8 __attribute__((ext_vector_type(8)));
typedef unsigned short ushx4 __attribute__((ext_vector_type(4)));
typedef float          fx4  __attribute__((ext_vector_type(4)));
typedef unsigned int   ux2  __attribute__((ext_vector_type(2)));

__device__ __forceinline__ void async16(const void* g, void* l) {
  __builtin_amdgcn_global_load_lds((__attribute__((address_space(1))) void*)g,
                                   (__attribute__((address_space(3))) void*)l,
                                   16, 0, 0);
}
__device__ __forceinline__ float b2f(u16 u) {
  union { unsigned int i; float f; } v; v.i = ((unsigned int)u) << 16; return v.f;
}
__device__ __forceinline__ u16 f2b(float f) {
  union { float f; unsigned int i; } v; v.f = f;
  unsigned int r = v.i + 0x7fffu + ((v.i >> 16) & 1u);
  return (u16)(r >> 16);
}
__device__ __forceinline__ ushx8 ld8(const void* p, long idx, bool f32) {
  if (f32) {
    const float* s = (const float*)p + idx;
    fx4 a = *(const fx4*)s, b = *(const fx4*)(s + 4);
    ushx8 r;
    r[0] = f2b(a[0]); r[1] = f2b(a[1]); r[2] = f2b(a[2]); r[3] = f2b(a[3]);
    r[4] = f2b(b[0]); r[5] = f2b(b[1]); r[6] = f2b(b[2]); r[7] = f2b(b[3]);
    return r;
  }
  return *(const ushx8*)((const u16*)p + idx);
}
__device__ __forceinline__ void ld4f(const void* p, long idx, bool f32, float* o) {
  if (f32) {
    fx4 a = *(const fx4*)((const float*)p + idx);
    o[0] = a[0]; o[1] = a[1]; o[2] = a[2]; o[3] = a[3];
  } else {
    ushx4 a = *(const ushx4*)((const u16*)p + idx);
    o[0] = b2f(a[0]); o[1] = b2f(a[1]); o[2] = b2f(a[2]); o[3] = b2f(a[3]);
  }
}

// ---------------------------------------------------------------------------
__global__ void detect_kernel(const void* q, int* flags) {
  int lane = threadIdx.x;
  u16 v = ((const u16*)q)[lane << 1];
  int e = (v >> 7) & 0xff;
  int pl = (e >= 0x60 && e <= 0x8c) ? 1 : 0;
  unsigned long long m = __ballot(pl);
  if (lane == 0) { flags[0] = (__popcll(m) >= 40) ? 0 : 1; flags[1] = 0; flags[2] = 1; }
}

// Scan mask for any zero; flags[2] stays 1 iff every element nonzero.
__global__ __launch_bounds__(256)
void mask_scan(const int* __restrict__ m, int* flags) {
  long i = (((long)blockIdx.x << 8) + threadIdx.x) << 3;
  const int4 a = *(const int4*)(m + i);
  const int4 b = *(const int4*)(m + i + 4);
  bool ok = a.x && a.y && a.z && a.w && b.x && b.y && b.z && b.w;
  if (!__all(ok)) { if ((threadIdx.x & 63) == 0) flags[2] = 0; }
}

// Pack Wq/Wk/Wv -> Wqkv [3*1024,1024] bf16 and Wo -> bf16.
__global__ __launch_bounds__(256)
void pack_w(const void* Wq, const void* Wk, const void* Wv, const void* Wo,
            u16* Wqkv, u16* Wo_bf, const int* f_p) {
  const bool f = (*f_p != 0);
  long i = (((long)blockIdx.x << 8) + threadIdx.x) << 3;
  const long QKVN = (long)3 * DM * DM;
  if (i < QKVN) {
    int row = (int)(i >> 10);
    const void* src = (row < DM) ? Wq : (row < 2 * DM ? Wk : Wv);
    long s = ((long)(row & (DM - 1)) << 10) + (i & 1023);
    *(ushx8*)(Wqkv + i) = ld8(src, s, f);
  } else {
    long j = i - QKVN;
    *(ushx8*)(Wo_bf + j) = ld8(Wo, j, f);
  }
}

// Convert q/k/v chunk to bf16; grid.y selects source, dst stride n.
__global__ __launch_bounds__(256)
void conv_bf3(const void* q, const void* k, const void* v, long off,
              u16* dst, long n, const int* f_p) {
  const bool f = (*f_p != 0);
  const void* src = (blockIdx.y == 0) ? q : (blockIdx.y == 1 ? k : v);
  long i = (((long)blockIdx.x << 8) + threadIdx.x) << 3;
  if (i < n) *(ushx8*)(dst + (long)blockIdx.y * n + i) = ld8(src, off + i, f);
}

// ---------------------------------------------------------------------------
// Pure-bf16 NT GEMM with global_load_lds(16B) staging. C=A@B^T (+bias)(+relu).
// grid.y = z selects (A,B,C) via element strides az/bz/cz. C row stride ldc.
// DBUF: double-buffered LDS with raw s_barrier + counted vmcnt(8) so the
// prefetch stays in flight ACROSS the barrier (T4). For 1-block/CU grids.
// ---------------------------------------------------------------------------
template<bool RELU, bool BIAS, bool DBUF>
__global__ __launch_bounds__(256)
void gemm_bb(const u16* __restrict__ A, long az, const u16* __restrict__ B, long bz,
             const void* __restrict__ bias, u16* __restrict__ C, long cz,
             int M, int N, int K, int ldc, const int* biasf_p) {
  __shared__ __align__(16) u16 sA[(DBUF ? 2 : 1) * 128 * 64];
  __shared__ __align__(16) u16 sB[(DBUF ? 2 : 1) * 128 * 64];
  const int z = blockIdx.y;
  A += (long)z * az; B += (long)z * bz; C += (long)z * cz;
  const bool biasf = BIAS && (*biasf_p != 0);
  const int t = threadIdx.x;
  const int lane = t & 63, w = t >> 6;
  const int lm = lane & 15, lg = lane >> 4;
  const int ntil = N >> 7;
  const int m0 = (blockIdx.x / ntil) << 7;
  const int n0 = (blockIdx.x % ntil) << 7;
  const int wm = (w & 1) << 6, wn = (w >> 1) << 6;

  fx4 acc[4][4];
#pragma unroll
  for (int i = 0; i < 4; ++i)
#pragma unroll
    for (int j = 0; j < 4; ++j) acc[i][j] = (fx4){0.f, 0.f, 0.f, 0.f};

  auto stage = [&](int so, int kt) {
#pragma unroll
    for (int it = 0; it < 4; ++it) {
      int ci = (it << 8) + t;
      int r = ci >> 3, cs = (ci & 7) ^ (r & 7);
      async16(&A[(size_t)(m0 + r) * K + kt + (cs << 3)], &sA[so + (ci << 3)]);
    }
#pragma unroll
    for (int it = 0; it < 4; ++it) {
      int ci = (it << 8) + t;
      int r = ci >> 3, cs = (ci & 7) ^ (r & 7);
      async16(&B[(size_t)(n0 + r) * K + kt + (cs << 3)], &sB[so + (ci << 3)]);
    }
  };

  auto compute = [&](int so) {
#pragma unroll
    for (int s = 0; s < 2; ++s) {
      const int g = (s << 2) + lg;
      sx8 afr[4], bfr[4];
#pragma unroll
      for (int i = 0; i < 4; ++i) {
        int ra = wm + (i << 4) + lm;
        afr[i] = *(const sx8*)&sA[so + ra * 64 + ((g ^ (ra & 7)) << 3)];
        int rb = wn + (i << 4) + lm;
        bfr[i] = *(const sx8*)&sB[so + rb * 64 + ((g ^ (rb & 7)) << 3)];
      }
#pragma unroll
      for (int i = 0; i < 4; ++i)
#pragma unroll
        for (int j = 0; j < 4; ++j)
          acc[i][j] = __builtin_amdgcn_mfma_f32_16x16x32_bf16(afr[i], bfr[j], acc[i][j], 0, 0, 0);
    }
  };

  if (DBUF) {
    const int NT = K >> 6;
    stage(0, 0);
    int cur = 0;
    for (int n = 0; n < NT; ++n) {
      __builtin_amdgcn_s_barrier();
      if (n + 1 < NT) {
        stage((cur ^ 1) << 13, (n + 1) << 6);   // prefetch next tile
        asm volatile("s_waitcnt vmcnt(8)" ::: "memory");   // current tile done
      } else {
        asm volatile("s_waitcnt vmcnt(0)" ::: "memory");
      }
      __builtin_amdgcn_sched_barrier(0);
      compute(cur << 13);
      cur ^= 1;
    }
  } else {
    for (int kt = 0; kt < K; kt += 64) {
      __syncthreads();
      stage(0, kt);
      __syncthreads();
      compute(0);
    }
  }

#pragma unroll
  for (int j = 0; j < 4; ++j) {
    const int col = n0 + wn + (j << 4) + lm;
    float bv = 0.f;
    if (BIAS) bv = biasf ? ((const float*)bias)[col] : b2f(((const u16*)bias)[col]);
#pragma unroll
    for (int i = 0; i < 4; ++i) {
      const int row0 = m0 + wm + (i << 4) + (lg << 2);
#pragma unroll
      for (int r = 0; r < 4; ++r) {
        float v = acc[i][j][r] + bv;
        if (RELU) v = fmaxf(v, 0.f);
        C[(size_t)(row0 + r) * ldc + col] = f2b(v);
      }
    }
  }
}

// ---------------------------------------------------------------------------
// Flag-dtype NT GEMM (legacy path, proven in round 3).
// ---------------------------------------------------------------------------
template<bool RELU, bool BIAS>
__global__ __launch_bounds__(256)
void gemm_nt(const void* __restrict__ A, long aoff, const void* __restrict__ Bm,
             const void* __restrict__ bias, u16* __restrict__ C,
             int M, int N, int K,
             const int* af_p, const int* bf_p, const int* biasf_p) {
  __shared__ __align__(16) u16 sA[128 * 64];
  __shared__ __align__(16) u16 sB[128 * 64];
  const bool af = (*af_p != 0), bfl = (*bf_p != 0), biasf = (*biasf_p != 0);
  const int t = threadIdx.x;
  const int lane = t & 63, w = t >> 6;
  const int lm = lane & 15, lg = lane >> 4;
  const int ntil = N >> 7;
  const int m0 = (blockIdx.x / ntil) << 7;
  const int n0 = (blockIdx.x % ntil) << 7;
  const int wm = (w & 1) << 6, wn = (w >> 1) << 6;

  fx4 acc[4][4];
#pragma unroll
  for (int i = 0; i < 4; ++i)
#pragma unroll
    for (int j = 0; j < 4; ++j) acc[i][j] = (fx4){0.f, 0.f, 0.f, 0.f};

  for (int kt = 0; kt < K; kt += 64) {
    __syncthreads();
#pragma unroll
    for (int it = 0; it < 4; ++it) {
      int ci = (it << 8) + t;
      int r = ci >> 3, cs = (ci & 7) ^ (r & 7);
      ushx8 va = ld8(A, aoff + (long)(m0 + r) * K + kt + (cs << 3), af);
      *(ushx8*)&sA[ci << 3] = va;
      ushx8 vb = ld8(Bm, (long)(n0 + r) * K + kt + (cs << 3), bfl);
      *(ushx8*)&sB[ci << 3] = vb;
    }
    __syncthreads();
#pragma unroll
    for (int s = 0; s < 2; ++s) {
      const int g = (s << 2) + lg;
      sx8 afr[4], bfr[4];
#pragma unroll
      for (int i = 0; i < 4; ++i) {
        int ra = wm + (i << 4) + lm;
        afr[i] = *(const sx8*)&sA[ra * 64 + ((g ^ (ra & 7)) << 3)];
        int rb = wn + (i << 4) + lm;
        bfr[i] = *(const sx8*)&sB[rb * 64 + ((g ^ (rb & 7)) << 3)];
      }
#pragma unroll
      for (int i = 0; i < 4; ++i)
#pragma unroll
        for (int j = 0; j < 4; ++j)
          acc[i][j] = __builtin_amdgcn_mfma_f32_16x16x32_bf16(afr[i], bfr[j], acc[i][j], 0, 0, 0);
    }
  }

#pragma unroll
  for (int j = 0; j < 4; ++j) {
    const int col = n0 + wn + (j << 4) + lm;
    float bv = 0.f;
    if (BIAS) bv = biasf ? ((const float*)bias)[col] : b2f(((const u16*)bias)[col]);
#pragma unroll
    for (int i = 0; i < 4; ++i) {
      const int row0 = m0 + wm + (i << 4) + (lg << 2);
#pragma unroll
      for (int r = 0; r < 4; ++r) {
        float v = acc[i][j][r] + bv;
        if (RELU) v = fmaxf(v, 0.f);
        C[(size_t)(row0 + r) * N + col] = f2b(v);
      }
    }
  }
}

// ---------------------------------------------------------------------------
__global__ __launch_bounds__(256)
void transpose_any(const void* __restrict__ in, u16* __restrict__ out,
                   int R, int C, const int* f_p) {
  __shared__ u16 tile[64][68];
  const bool f = (*f_p != 0);
  const int r0 = blockIdx.y << 6, c0 = blockIdx.x << 6;
  const int t = threadIdx.x;
#pragma unroll
  for (int it = 0; it < 4; ++it) {
    int j = (it << 8) + t;
    int rr = j >> 4, cc4 = (j & 15) << 2;
    float v[4];
    ld4f(in, (long)(r0 + rr) * C + c0 + cc4, f, v);
#pragma unroll
    for (int q = 0; q < 4; ++q) tile[rr][cc4 + q] = f2b(v[q]);
  }
  __syncthreads();
#pragma unroll
  for (int it = 0; it < 4; ++it) {
    int j = (it << 8) + t;
    int cc = j >> 4, rr4 = (j & 15) << 2;
    ushx4 v;
    v[0] = tile[rr4 + 0][cc]; v[1] = tile[rr4 + 1][cc];
    v[2] = tile[rr4 + 2][cc]; v[3] = tile[rr4 + 3][cc];
    *(ushx4*)&out[(size_t)(c0 + cc) * R + r0 + rr4] = v;
  }
}

// ---------------------------------------------------------------------------
// Flash attention, swapped-QK^T structure.
// grid.x = 512 (h<<5|qblock after XCD swizzle); grid.y = batch.
// Per wave: 16 q rows. QK^T computed as mfma(K,Q) so lane (lm,lg) holds
// S[q=lm][k = nt*16+lg*4+r] -> softmax is per-lane + 2 shfls. P packed to
// bf16 via v_cvt_pk_bf16_f32; PV A-fragments assembled by register shuffles
// (no P LDS round-trip). LDS = sK(16K) + sVt(17K) -> 4 blocks/CU.
// ---------------------------------------------------------------------------
__global__ __launch_bounds__(256, 4)
void attn_kernel(const u16* __restrict__ qp, const u16* __restrict__ kp,
                 const u16* __restrict__ vp, int lds_,
                 const int* __restrict__ mask, u16* __restrict__ ctx,
                 const int* __restrict__ mflag) {
  __shared__ __align__(16) u16 sK[128 * 64];
  __shared__ __align__(16) u16 sVt[64 * 136];

  const bool nomask = (*mflag != 0);
  const long boff = (long)blockIdx.y * SEQ * (long)lds_;
  qp += boff; kp += boff; vp += boff;
  mask += (size_t)blockIdx.y * ((size_t)SEQ * SEQ);
  ctx += (size_t)blockIdx.y * ((size_t)SEQ * DM);

  // XCD-aware swizzle (bijective: gridDim.x % 8 == 0): consecutive swizzled
  // ids (same head -> same K/V) land on one XCD's L2.
  const int id = (blockIdx.x & 7) * ((int)gridDim.x >> 3) + (blockIdx.x >> 3);
  const int q0 = (id & 31) << 6;
  const int h  = id >> 5;
  const int t = threadIdx.x, lane = t & 63, w = t >> 6;
  const int hoff = h << 6;
  const int lm = lane & 15, lg = lane >> 4;
  const int myq = q0 + (w << 4) + lm;        // this lane's softmax row
  const int aslot = 20 * lg;                  // shfl src base: lane lg*16 + (lg*4+r)
  const int srcA = ((lane >> 4) & 1) * 32 + lm;  // PV exchange source (g0/g2)

  // Q fragments (this lane = B-row lm of the swapped mfma): row myq, octets lg, 4+lg
  sx8 aq[2];
#pragma unroll
  for (int s = 0; s < 2; ++s)
    aq[s] = *(const sx8*)&qp[(size_t)myq * lds_ + hoff + (((s << 2) + lg) << 3)];

  fx4 o[4];
#pragma unroll
  for (int i = 0; i < 4; ++i) o[i] = (fx4){0.f, 0.f, 0.f, 0.f};
  float m_prev = -1e30f, lsum = 0.f;
  const float SCL = 0.18033688f;  // 0.125 * log2(e): softmax in log2 domain

  for (int kt = 0; kt < 16; ++kt) {
    const int k0 = kt << 7;
    __syncthreads();
    // K -> sK via global_load_lds (swizzled source, linear LDS)
#pragma unroll
    for (int it = 0; it < 4; ++it) {
      int ci = (it << 8) + t;
      int r = ci >> 3, cs = (ci & 7) ^ (r & 7);
      async16(&kp[(size_t)(k0 + r) * lds_ + hoff + (cs << 3)], &sK[ci << 3]);
    }
    // V -> sVt transposed: thread owns 4 keys x 8 d; v_perm packs pairs,
    // 8x 8B LDS writes.
    {
      const int kq = (t & 31) << 2, dg = (t >> 5) << 3;
      const uint4 v0 = *(const uint4*)&vp[(size_t)(k0 + kq + 0) * lds_ + hoff + dg];
      const uint4 v1 = *(const uint4*)&vp[(size_t)(k0 + kq + 1) * lds_ + hoff + dg];
      const uint4 v2 = *(const uint4*)&vp[(size_t)(k0 + kq + 2) * lds_ + hoff + dg];
      const uint4 v3 = *(const uint4*)&vp[(size_t)(k0 + kq + 3) * lds_ + hoff + dg];
      const unsigned A[4] = {v0.x, v0.y, v0.z, v0.w};
      const unsigned B[4] = {v1.x, v1.y, v1.z, v1.w};
      const unsigned Cc[4] = {v2.x, v2.y, v2.z, v2.w};
      const unsigned D[4] = {v3.x, v3.y, v3.z, v3.w};
#pragma unroll
      for (int j = 0; j < 8; ++j) {
        const unsigned sel = (j & 1) ? 0x07060302u : 0x05040100u;
        ux2 wv;
        wv.x = __builtin_amdgcn_perm(B[j >> 1], A[j >> 1], sel);
        wv.y = __builtin_amdgcn_perm(D[j >> 1], Cc[j >> 1], sel);
        *(ux2*)&sVt[(size_t)(dg + j) * 136 + kq] = wv;
      }
    }
    __syncthreads();

    // QK^T swapped: sc[nt] = S^T tile -> lane holds S[q=lm][k=nt*16+lg*4+r]
    fx4 sc[8];
#pragma unroll
    for (int nt = 0; nt < 8; ++nt) sc[nt] = (fx4){0.f, 0.f, 0.f, 0.f};
#pragma unroll
    for (int s = 0; s < 2; ++s) {
      const int g = (s << 2) + lg;
#pragma unroll
      for (int nt = 0; nt < 8; ++nt) {
        int rk = (nt << 4) + lm;
        sx8 bk = *(const sx8*)&sK[rk * 64 + ((g ^ (rk & 7)) << 3)];
        sc[nt] = __builtin_amdgcn_mfma_f32_16x16x32_bf16(bk, aq[s], sc[nt], 0, 0, 0);
      }
    }

    // softmax (log2 domain), per-lane row + cross-group reduce
    float pv[8][4];
    float tm = -1e30f;
#pragma unroll
    for (int nt = 0; nt < 8; ++nt)
#pragma unroll
      for (int r = 0; r < 4; ++r) {
        float v = sc[nt][r] * SCL;
        if (!nomask) {
          const int col = k0 + (nt << 4) + (lg << 2) + r;
          if (mask[((size_t)myq << 11) + col] == 0) v = -1e9f;
        }
        pv[nt][r] = v;
        tm = fmaxf(tm, v);
      }
    tm = fmaxf(tm, __shfl_xor(tm, 16));
    tm = fmaxf(tm, __shfl_xor(tm, 32));

    const float mold = m_prev;
    if (!__all(tm <= mold + 8.0f)) {      // defer-max: skip rescale if bounded
      m_prev = fmaxf(mold, tm);
      float alpha = exp2f(mold - m_prev);
      lsum *= alpha;
#pragma unroll
      for (int r = 0; r < 4; ++r) {
        float ar = __shfl(alpha, aslot + r);
#pragma unroll
        for (int ot = 0; ot < 4; ++ot) o[ot][r] *= ar;
      }
    }

    float rs = 0.f;
#pragma unroll
    for (int nt = 0; nt < 8; ++nt)
#pragma unroll
      for (int r = 0; r < 4; ++r) {
        float e = exp2f(pv[nt][r] - m_prev);
        pv[nt][r] = e;
        rs += e;
      }
    rs += __shfl_xor(rs, 16);
    rs += __shfl_xor(rs, 32);
    lsum += rs;

    // P -> bf16 pairs (r0,r1),(r2,r3) per nt
    unsigned cpk[8][2];
#pragma unroll
    for (int nt = 0; nt < 8; ++nt) {
      asm("v_cvt_pk_bf16_f32 %0, %1, %2" : "=v"(cpk[nt][0]) : "v"(pv[nt][0]), "v"(pv[nt][1]));
      asm("v_cvt_pk_bf16_f32 %0, %1, %2" : "=v"(cpk[nt][1]) : "v"(pv[nt][2]), "v"(pv[nt][3]));
    }

    // PV: build A-fragment (P[q=lm][k=ks*32+lg*8+e]) by lane exchange:
    // words 0,1 from src lane srcA (group 2lg&3), words 2,3 from srcA+16;
    // nt = 2ks for lg<2, 2ks+1 for lg>=2.
#pragma unroll
    for (int ks = 0; ks < 4; ++ks) {
      const unsigned d0 = cpk[2 * ks][0], d1 = cpk[2 * ks][1];
      const unsigned e0 = cpk[2 * ks + 1][0], e1 = cpk[2 * ks + 1][1];
      const unsigned w0d = (unsigned)__shfl((int)d0, srcA);
      const unsigned w0e = (unsigned)__shfl((int)e0, srcA);
      const unsigned w1d = (unsigned)__shfl((int)d1, srcA);
      const unsigned w1e = (unsigned)__shfl((int)e1, srcA);
      const unsigned w2d = (unsigned)__shfl((int)d0, srcA + 16);
      const unsigned w2e = (unsigned)__shfl((int)e0, srcA + 16);
      const unsigned w3d = (unsigned)__shfl((int)d1, srcA + 16);
      const unsigned w3e = (unsigned)__shfl((int)e1, srcA + 16);
      const bool lo = (lg < 2);
      union { unsigned u[4]; sx8 v; } ap;
      ap.u[0] = lo ? w0d : w0e;
      ap.u[1] = lo ? w1d : w1e;
      ap.u[2] = lo ? w2d : w2e;
      ap.u[3] = lo ? w3d : w3e;
#pragma unroll
      for (int ot = 0; ot < 4; ++ot) {
        int d = (ot << 4) + lm;
        sx8 bv = *(const sx8*)&sVt[d * 136 + (ks << 5) + (lg << 3)];
        o[ot] = __builtin_amdgcn_mfma_f32_16x16x32_bf16(ap.v, bv, o[ot], 0, 0, 0);
      }
    }
  }

  float inv = (lsum > 0.f) ? 1.f / lsum : 0.f;
#pragma unroll
  for (int r = 0; r < 4; ++r) {
    float ir = __shfl(inv, aslot + r);
#pragma unroll
    for (int ot = 0; ot < 4; ++ot) {
      const int rowg = q0 + (w << 4) + (lg << 2) + r;
      const int col = hoff + (ot << 4) + lm;
      ctx[((size_t)rowg << 10) + col] = f2b(o[ot][r] * ir);
    }
  }
}

// ---------------------------------------------------------------------------
__global__ __launch_bounds__(256)
void ln_dual(const u16* __restrict__ a, const void* __restrict__ res, long roff,
             const void* __restrict__ g1, const void* __restrict__ b1,
             const void* __restrict__ gf, const void* __restrict__ bf,
             u16* __restrict__ xo, u16* __restrict__ xlo, const int* f_p) {
  __shared__ float red[8];
  const bool f = (*f_p != 0);
  const int row = blockIdx.x, t = threadIdx.x;
  const int lane = t & 63, w = t >> 6;
  const size_t base = (size_t)row << 10;
  const int c = t << 2;

  ushx4 a4 = *(const ushx4*)(a + base + c);
  float rv[4];
  ld4f(res, roff + (long)base + c, f, rv);
  float v[4], s = 0.f, ss = 0.f;
#pragma unroll
  for (int j = 0; j < 4; ++j) { v[j] = b2f(a4[j]) + rv[j]; s += v[j]; ss += v[j] * v[j]; }
#pragma unroll
  for (int off = 32; off > 0; off >>= 1) { s += __shfl_xor(s, off); ss += __shfl_xor(ss, off); }
  if (lane == 0) { red[w] = s; red[4 + w] = ss; }
  __syncthreads();
  s = red[0] + red[1] + red[2] + red[3];
  ss = red[4] + red[5] + red[6] + red[7];
  float mu = s * (1.f / 1024.f);
  float rstd = rsqrtf(fmaxf(ss * (1.f / 1024.f) - mu * mu, 0.f) + 1e-5f);

  float g4[4], b4[4];
  ld4f(g1, c, f, g4); ld4f(b1, c, f, b4);
  float x[4], s2 = 0.f, ss2 = 0.f;
  ushx4 xo4;
#pragma unroll
  for (int j = 0; j < 4; ++j) {
    x[j] = (v[j] - mu) * rstd * g4[j] + b4[j];
    xo4[j] = f2b(x[j]);
    s2 += x[j]; ss2 += x[j] * x[j];
  }
  *(ushx4*)(xo + base + c) = xo4;
#pragma unroll
  for (int off = 32; off > 0; off >>= 1) { s2 += __shfl_xor(s2, off); ss2 += __shfl_xor(ss2, off); }
  __syncthreads();
  if (lane == 0) { red[w] = s2; red[4 + w] = ss2; }
  __syncthreads();
  s2 = red[0] + red[1] + red[2] + red[3];
  ss2 = red[4] + red[5] + red[6] + red[7];
  float mu2 = s2 * (1.f / 1024.f);
  float rstd2 = rsqrtf(fmaxf(ss2 * (1.f / 1024.f) - mu2 * mu2, 0.f) + 1e-5f);

  ld4f(gf, c, f, g4); ld4f(bf, c, f, b4);
  ushx4 xl4;
#pragma unroll
  for (int j = 0; j < 4; ++j)
    xl4[j] = f2b((x[j] - mu2) * rstd2 * g4[j] + b4[j]);
  *(ushx4*)(xlo + base + c) = xl4;
}

// ---------------------------------------------------------------------------
__global__ __launch_bounds__(256)
void ln_final(const u16* __restrict__ a, const u16* __restrict__ resx,
              const void* __restrict__ g, const void* __restrict__ bb,
              void* __restrict__ out, long ooff, const int* f_p) {
  __shared__ float red[8];
  const bool f = (*f_p != 0);
  const int row = blockIdx.x, t = threadIdx.x;
  const int lane = t & 63, w = t >> 6;
  const size_t base = (size_t)row << 10;
  const int c = t << 2;

  ushx4 a4 = *(const ushx4*)(a + base + c);
  ushx4 r4 = *(const ushx4*)(resx + base + c);
  float v[4], s = 0.f, ss = 0.f;
#pragma unroll
  for (int j = 0; j < 4; ++j) { v[j] = b2f(a4[j]) + b2f(r4[j]); s += v[j]; ss += v[j] * v[j]; }
#pragma unroll
  for (int off = 32; off > 0; off >>= 1) { s += __shfl_xor(s, off); ss += __shfl_xor(ss, off); }
  if (lane == 0) { red[w] = s; red[4 + w] = ss; }
  __syncthreads();
  s = red[0] + red[1] + red[2] + red[3];
  ss = red[4] + red[5] + red[6] + red[7];
  float mu = s * (1.f / 1024.f);
  float rstd = rsqrtf(fmaxf(ss * (1.f / 1024.f) - mu * mu, 0.f) + 1e-5f);

  float g4[4], b4[4];
  ld4f(g, c, f, g4); ld4f(bb, c, f, b4);
  if (f) {
    fx4 o4;
#pragma unroll
    for (int j = 0; j < 4; ++j) o4[j] = (v[j] - mu) * rstd * g4[j] + b4[j];
    *(fx4*)((float*)out + ooff + base + c) = o4;
  } else {
    ushx4 o4;
#pragma unroll
    for (int j = 0; j < 4; ++j) o4[j] = f2b((v[j] - mu) * rstd * g4[j] + b4[j]);
    *(ushx4*)((u16*)out + ooff + base + c) = o4;
  }
}

// ---------------------------------------------------------------------------
extern "C" void kernel_launch(void* const* d_in, const int* in_sizes, int n_in,
                              void* d_out, int out_size, void* d_ws, size_t ws_size,
                              hipStream_t stream) {
  (void)in_sizes; (void)n_in; (void)out_size;
  const void* query = d_in[0];
  const void* keyi  = d_in[1];
  const void* value = d_in[2];
  const int*  mask  = (const int*)d_in[3];
  const void* Wq = d_in[4];
  const void* Wk = d_in[5];
  const void* Wv = d_in[6];
  const void* Wo = d_in[7];
  const void* bo = d_in[8];
  const void* g1 = d_in[9];
  const void* b1 = d_in[10];
  const void* g2 = d_in[11];
  const void* b2 = d_in[12];
  const void* gff = d_in[13];
  const void* bff = d_in[14];
  const void* W1 = d_in[15];
  const void* bf1 = d_in[16];
  const void* W2 = d_in[17];
  const void* bf2 = d_in[18];

  char* p = (char*)d_ws;
  int* flags = (int*)p;
  const int* F = flags;
  const int* Z = flags + 1;
  const int* M = flags + 2;
  dim3 blk(256);

  // footprint(CH) = 4096 + 24MiB (packed weights) + 7*CH*2048 bytes
  const size_t FIXED = 4096 + ((size_t)24 << 20);
  const size_t needA = FIXED + (size_t)4096 * 14336;   // ~80.0 MB
  const size_t needB = FIXED + (size_t)2048 * 14336;   // ~52.0 MB

  if (ws_size >= needB) {
    // ------------------------- NEW PATH -------------------------
    const int CH = (ws_size >= needA) ? 4096 : 2048;
    const int nch = 8192 / CH;

    u16* Wqkv  = (u16*)(p + 4096);                       // [3*1024,1024]
    u16* Wo_bf = Wqkv + (size_t)3 * DM * DM;             // [1024,1024]
    u16* W1T   = Wo_bf + (size_t)DM * DM;                // [4096,1024]
    u16* W2T   = W1T + (size_t)DFF * DM;                 // [1024,4096]
    u16* D0    = W2T + (size_t)DM * DFF;                 // in_bf / h
    u16* D1    = D0 + (size_t)3 * CH * DM;               // qkv / ao,x,xln
    u16* D2    = D1 + (size_t)3 * CH * DM;               // ctx / ff
    u16* qb = D0;
    u16* qkv = D1;
    u16* ao = D1, *x = D1 + (size_t)CH * DM, *xln = D1 + (size_t)2 * CH * DM;
    u16* h = D0;                                         // CH*4096 elems
    u16* ctx = D2, *ff = D2;

    detect_kernel<<<1, 64, 0, stream>>>(query, flags);
    mask_scan<<<dim3(8192), blk, 0, stream>>>(mask, flags);
    pack_w<<<dim3(2048), blk, 0, stream>>>(Wq, Wk, Wv, Wo, Wqkv, Wo_bf, F);
    transpose_any<<<dim3(DFF / 64, DM / 64), blk, 0, stream>>>(W1, W1T, DM, DFF, F);
    transpose_any<<<dim3(DM / 64, DFF / 64), blk, 0, stream>>>(W2, W2T, DFF, DM, F);

    for (int c = 0; c < nch; ++c) {
      const long off = (long)c * CH * DM;
      const long n = (long)CH * DM;
      conv_bf3<<<dim3((int)(n >> 11), 3), blk, 0, stream>>>(query, keyi, value, off, qb, n, F);

      // q/k/v projections co-dispatched: z in {0,1,2}
      gemm_bb<false, false, false><<<dim3((CH / 128) * 8, 3), blk, 0, stream>>>(
          qb, (long)CH * DM, Wqkv, (long)DM * DM, nullptr,
          qkv, 1024L, CH, DM, DM, 3072, Z);

      const int bpc = CH / SEQ, b0 = c * bpc;
      attn_kernel<<<dim3(512, bpc), blk, 0, stream>>>(
          qkv, qkv + 1024, qkv + 2048, 3072,
          mask + (size_t)b0 * SEQ * SEQ, ctx, M);

      gemm_bb<false, true, true><<<dim3((CH / 128) * 8, 1), blk, 0, stream>>>(
          ctx, 0, Wo_bf, 0, bo, ao, 0, CH, DM, DM, DM, F);

      ln_dual<<<dim3(CH), blk, 0, stream>>>(ao, query, off, g1, b1, gff, bff, x, xln, F);

      gemm_bb<true, true, false><<<dim3((CH / 128) * 32, 1), blk, 0, stream>>>(
          xln, 0, W1T, 0, bf1, h, 0, CH, DFF, DM, DFF, F);
      gemm_bb<false, true, true><<<dim3((CH / 128) * 8, 1), blk, 0, stream>>>(
          h, 0, W2T, 0, bf2, ff, 0, CH, DM, DFF, DM, F);

      ln_final<<<dim3(CH), blk, 0, stream>>>(ff, x, g2, b2, d_out, off, F);
    }
  } else {
    // ------------------------- LEGACY PATH (round-3 proven) -------------------------
    const int CH = 2048, FH = 1024;
    const int nch = 8192 / CH;
    const size_t h0 = 4096;
    u16* W1T = (u16*)(p + h0);
    u16* W2T = W1T + (size_t)DFF * DM;
    u16* hb  = (u16*)(p + h0 + ((size_t)16 << 20));
    const size_t HB = (size_t)FH * DFF * 2;
    u16* r0 = (u16*)(p + h0 + ((size_t)16 << 20) + HB);
    const size_t CE = (size_t)CH * DM;
    u16* qp = r0;
    u16* kp = qp + CE;
    u16* vp = kp + CE;
    u16* ctxb = vp + CE;
    u16* x = qp; u16* xln = kp; u16* ao = vp; u16* ff = ctxb;

    detect_kernel<<<1, 64, 0, stream>>>(query, flags);
    mask_scan<<<dim3(8192), blk, 0, stream>>>(mask, flags);
    transpose_any<<<dim3(DFF / 64, DM / 64), blk, 0, stream>>>(W1, W1T, DM, DFF, F);
    transpose_any<<<dim3(DM / 64, DFF / 64), blk, 0, stream>>>(W2, W2T, DFF, DM, F);

    for (int c = 0; c < nch; ++c) {
      const long off = (long)c * CH * DM;
      dim3 gq((CH / 128) * (DM / 128));

      gemm_nt<false, false><<<gq, blk, 0, stream>>>(query, off, Wq, Wq, qp, CH, DM, DM, F, F, Z);
      gemm_nt<false, false><<<gq, blk, 0, stream>>>(keyi,  off, Wk, Wk, kp, CH, DM, DM, F, F, Z);
      gemm_nt<false, false><<<gq, blk, 0, stream>>>(value, off, Wv, Wv, vp, CH, DM, DM, F, F, Z);

      const int bpc = CH / SEQ, b0 = c * bpc;
      for (int bl = 0; bl < bpc; ++bl) {
        const size_t lo = (size_t)bl * SEQ * DM;
        attn_kernel<<<dim3(512, 1), blk, 0, stream>>>(
            qp + lo, kp + lo, vp + lo, 1024,
            mask + (size_t)(b0 + bl) * SEQ * SEQ, ctxb + lo, M);
      }

      gemm_nt<false, true><<<gq, blk, 0, stream>>>(ctxb, 0, Wo, bo, ao, CH, DM, DM, Z, F, F);

      ln_dual<<<dim3(CH), blk, 0, stream>>>(ao, query, off, g1, b1, gff, bff, x, xln, F);

      for (int qs = 0; qs < CH / FH; ++qs) {
        const long so = (long)qs * FH * DM;
        gemm_nt<true, true><<<dim3((FH / 128) * (DFF / 128)), blk, 0, stream>>>(
            xln + so, 0, W1T, bf1, hb, FH, DFF, DM, Z, Z, F);
        gemm_nt<false, true><<<dim3((FH / 128) * (DM / 128)), blk, 0, stream>>>(
            hb, 0, W2T, bf2, ff + so, FH, DM, DFF, Z, Z, F);
      }

      ln_final<<<dim3(CH), blk, 0, stream>>>(ff, x, g2, b2, d_out, off, F);
    }
  }
}

// Round 3
// 830.620 us; speedup vs baseline: 1.1343x; 1.0002x over previous
//
#include <hip/hip_runtime.h>

// ---------------------------------------------------------------------------
// SublayerConnection: MHA + residual/LN + FF + residual/LN
// B=4 S=2048 D=1024 H=16 Dk=64 Dff=4096.
// Round 7: attn: bpermute-exchange -> wave-local swizzled sP2 LDS (8 b64
// writes + 4 b128 reads), K/V reg-staged one tile ahead (T14), sVt write
// row-swizzle (kills 4-way conflict), raw-domain softmax (fma into exp),
// setprio on MFMA clusters. gemm_bb DBUF -> depth-2 prefetch (3 LDS bufs,
// vmcnt(16)), XCD-swizzle on all gemm grids. CH=8192 tier if ws allows.
// ---------------------------------------------------------------------------

#define DM   1024
#define DFF  4096
#define SEQ  2048

typedef unsigned short u16;
typedef short          sx8  __attribute__((ext_vector_type(8)));
typedef unsigned short ushx8 __attribute__((ext_vector_type(8)));
typedef unsigned short ushx4 __attribute__((ext_vector_type(4)));
typedef float          fx4  __attribute__((ext_vector_type(4)));
typedef unsigned int   ux2  __attribute__((ext_vector_type(2)));

__device__ __forceinline__ void async16(const void* g, void* l) {
  __builtin_amdgcn_global_load_lds((__attribute__((address_space(1))) void*)g,
                                   (__attribute__((address_space(3))) void*)l,
                                   16, 0, 0);
}
__device__ __forceinline__ float b2f(u16 u) {
  union { unsigned int i; float f; } v; v.i = ((unsigned int)u) << 16; return v.f;
}
__device__ __forceinline__ u16 f2b(float f) {
  union { float f; unsigned int i; } v; v.f = f;
  unsigned int r = v.i + 0x7fffu + ((v.i >> 16) & 1u);
  return (u16)(r >> 16);
}
__device__ __forceinline__ float fexp2(float x) {
#if __has_builtin(__builtin_amdgcn_exp2f)
  return __builtin_amdgcn_exp2f(x);
#else
  return exp2f(x);
#endif
}
__device__ __forceinline__ ushx8 ld8(const void* p, long idx, bool f32) {
  if (f32) {
    const float* s = (const float*)p + idx;
    fx4 a = *(const fx4*)s, b = *(const fx4*)(s + 4);
    ushx8 r;
    r[0] = f2b(a[0]); r[1] = f2b(a[1]); r[2] = f2b(a[2]); r[3] = f2b(a[3]);
    r[4] = f2b(b[0]); r[5] = f2b(b[1]); r[6] = f2b(b[2]); r[7] = f2b(b[3]);
    return r;
  }
  return *(const ushx8*)((const u16*)p + idx);
}
__device__ __forceinline__ void ld4f(const void* p, long idx, bool f32, float* o) {
  if (f32) {
    fx4 a = *(const fx4*)((const float*)p + idx);
    o[0] = a[0]; o[1] = a[1]; o[2] = a[2]; o[3] = a[3];
  } else {
    ushx4 a = *(const ushx4*)((const u16*)p + idx);
    o[0] = b2f(a[0]); o[1] = b2f(a[1]); o[2] = b2f(a[2]); o[3] = b2f(a[3]);
  }
}

// ---------------------------------------------------------------------------
__global__ void detect_kernel(const void* q, int* flags) {
  int lane = threadIdx.x;
  u16 v = ((const u16*)q)[lane << 1];
  int e = (v >> 7) & 0xff;
  int pl = (e >= 0x60 && e <= 0x8c) ? 1 : 0;
  unsigned long long m = __ballot(pl);
  if (lane == 0) { flags[0] = (__popcll(m) >= 40) ? 0 : 1; flags[1] = 0; flags[2] = 1; }
}

// Scan mask for any zero; flags[2] stays 1 iff every element nonzero.
__global__ __launch_bounds__(256)
void mask_scan(const int* __restrict__ m, int* flags) {
  long i = (((long)blockIdx.x << 8) + threadIdx.x) << 3;
  const int4 a = *(const int4*)(m + i);
  const int4 b = *(const int4*)(m + i + 4);
  bool ok = a.x && a.y && a.z && a.w && b.x && b.y && b.z && b.w;
  if (!__all(ok)) { if ((threadIdx.x & 63) == 0) flags[2] = 0; }
}

// Pack Wq/Wk/Wv -> Wqkv [3*1024,1024] bf16 and Wo -> bf16.
__global__ __launch_bounds__(256)
void pack_w(const void* Wq, const void* Wk, const void* Wv, const void* Wo,
            u16* Wqkv, u16* Wo_bf, const int* f_p) {
  const bool f = (*f_p != 0);
  long i = (((long)blockIdx.x << 8) + threadIdx.x) << 3;
  const long QKVN = (long)3 * DM * DM;
  if (i < QKVN) {
    int row = (int)(i >> 10);
    const void* src = (row < DM) ? Wq : (row < 2 * DM ? Wk : Wv);
    long s = ((long)(row & (DM - 1)) << 10) + (i & 1023);
    *(ushx8*)(Wqkv + i) = ld8(src, s, f);
  } else {
    long j = i - QKVN;
    *(ushx8*)(Wo_bf + j) = ld8(Wo, j, f);
  }
}

// Convert q/k/v chunk to bf16; grid.y selects source, dst stride n.
__global__ __launch_bounds__(256)
void conv_bf3(const void* q, const void* k, const void* v, long off,
              u16* dst, long n, const int* f_p) {
  const bool f = (*f_p != 0);
  const void* src = (blockIdx.y == 0) ? q : (blockIdx.y == 1 ? k : v);
  long i = (((long)blockIdx.x << 8) + threadIdx.x) << 3;
  if (i < n) *(ushx8*)(dst + (long)blockIdx.y * n + i) = ld8(src, off + i, f);
}

// ---------------------------------------------------------------------------
// Pure-bf16 NT GEMM with global_load_lds(16B) staging. C=A@B^T (+bias)(+relu).
// grid.y = z selects (A,B,C) via element strides az/bz/cz. C row stride ldc.
// DBUF: 3 LDS buffers, prefetch depth 2, counted vmcnt(16) so two tiles of
// loads stay in flight across barriers (T3/T4). For 1-2 block/CU grids.
// All grids are %8==0 -> bijective XCD swizzle for L2 A-tile sharing.
// ---------------------------------------------------------------------------
template<bool RELU, bool BIAS, bool DBUF>
__global__ __launch_bounds__(256)
void gemm_bb(const u16* __restrict__ A, long az, const u16* __restrict__ B, long bz,
             const void* __restrict__ bias, u16* __restrict__ C, long cz,
             int M, int N, int K, int ldc, const int* biasf_p) {
  __shared__ __align__(16) u16 sA[(DBUF ? 3 : 1) * 128 * 64];
  __shared__ __align__(16) u16 sB[(DBUF ? 3 : 1) * 128 * 64];
  const int z = blockIdx.y;
  A += (long)z * az; B += (long)z * bz; C += (long)z * cz;
  const bool biasf = BIAS && (*biasf_p != 0);
  const int t = threadIdx.x;
  const int lane = t & 63, w = t >> 6;
  const int lm = lane & 15, lg = lane >> 4;
  const int ntil = N >> 7;
  // XCD-aware bijective swizzle (gridDim.x % 8 == 0 for all dispatches)
  const int bx = (blockIdx.x & 7) * ((int)gridDim.x >> 3) + (blockIdx.x >> 3);
  const int m0 = (bx / ntil) << 7;
  const int n0 = (bx % ntil) << 7;
  const int wm = (w & 1) << 6, wn = (w >> 1) << 6;

  fx4 acc[4][4];
#pragma unroll
  for (int i = 0; i < 4; ++i)
#pragma unroll
    for (int j = 0; j < 4; ++j) acc[i][j] = (fx4){0.f, 0.f, 0.f, 0.f};

  auto stage = [&](int so, int kt) {
#pragma unroll
    for (int it = 0; it < 4; ++it) {
      int ci = (it << 8) + t;
      int r = ci >> 3, cs = (ci & 7) ^ (r & 7);
      async16(&A[(size_t)(m0 + r) * K + kt + (cs << 3)], &sA[so + (ci << 3)]);
    }
#pragma unroll
    for (int it = 0; it < 4; ++it) {
      int ci = (it << 8) + t;
      int r = ci >> 3, cs = (ci & 7) ^ (r & 7);
      async16(&B[(size_t)(n0 + r) * K + kt + (cs << 3)], &sB[so + (ci << 3)]);
    }
  };

  auto compute = [&](int so) {
#pragma unroll
    for (int s = 0; s < 2; ++s) {
      const int g = (s << 2) + lg;
      sx8 afr[4], bfr[4];
#pragma unroll
      for (int i = 0; i < 4; ++i) {
        int ra = wm + (i << 4) + lm;
        afr[i] = *(const sx8*)&sA[so + ra * 64 + ((g ^ (ra & 7)) << 3)];
        int rb = wn + (i << 4) + lm;
        bfr[i] = *(const sx8*)&sB[so + rb * 64 + ((g ^ (rb & 7)) << 3)];
      }
      __builtin_amdgcn_s_setprio(1);
#pragma unroll
      for (int i = 0; i < 4; ++i)
#pragma unroll
        for (int j = 0; j < 4; ++j)
          acc[i][j] = __builtin_amdgcn_mfma_f32_16x16x32_bf16(afr[i], bfr[j], acc[i][j], 0, 0, 0);
      __builtin_amdgcn_s_setprio(0);
    }
  };

  if (DBUF) {
    const int NT = K >> 6;
    stage(0, 0);
    if (NT > 1) stage(8192, 64);
    for (int n = 0; n < NT; ++n) {
      __builtin_amdgcn_s_barrier();
      if (n + 2 < NT) {
        stage(((n + 2) % 3) << 13, (n + 2) << 6);
        asm volatile("s_waitcnt vmcnt(16)" ::: "memory");
      } else if (n + 1 < NT) {
        asm volatile("s_waitcnt vmcnt(8)" ::: "memory");
      } else {
        asm volatile("s_waitcnt vmcnt(0)" ::: "memory");
      }
      __builtin_amdgcn_sched_barrier(0);
      compute((n % 3) << 13);
    }
  } else {
    for (int kt = 0; kt < K; kt += 64) {
      __syncthreads();
      stage(0, kt);
      __syncthreads();
      compute(0);
    }
  }

#pragma unroll
  for (int j = 0; j < 4; ++j) {
    const int col = n0 + wn + (j << 4) + lm;
    float bv = 0.f;
    if (BIAS) bv = biasf ? ((const float*)bias)[col] : b2f(((const u16*)bias)[col]);
#pragma unroll
    for (int i = 0; i < 4; ++i) {
      const int row0 = m0 + wm + (i << 4) + (lg << 2);
#pragma unroll
      for (int r = 0; r < 4; ++r) {
        float v = acc[i][j][r] + bv;
        if (RELU) v = fmaxf(v, 0.f);
        C[(size_t)(row0 + r) * ldc + col] = f2b(v);
      }
    }
  }
}

// ---------------------------------------------------------------------------
// Flag-dtype NT GEMM (legacy path, proven in round 3).
// ---------------------------------------------------------------------------
template<bool RELU, bool BIAS>
__global__ __launch_bounds__(256)
void gemm_nt(const void* __restrict__ A, long aoff, const void* __restrict__ Bm,
             const void* __restrict__ bias, u16* __restrict__ C,
             int M, int N, int K,
             const int* af_p, const int* bf_p, const int* biasf_p) {
  __shared__ __align__(16) u16 sA[128 * 64];
  __shared__ __align__(16) u16 sB[128 * 64];
  const bool af = (*af_p != 0), bfl = (*bf_p != 0), biasf = (*biasf_p != 0);
  const int t = threadIdx.x;
  const int lane = t & 63, w = t >> 6;
  const int lm = lane & 15, lg = lane >> 4;
  const int ntil = N >> 7;
  const int m0 = (blockIdx.x / ntil) << 7;
  const int n0 = (blockIdx.x % ntil) << 7;
  const int wm = (w & 1) << 6, wn = (w >> 1) << 6;

  fx4 acc[4][4];
#pragma unroll
  for (int i = 0; i < 4; ++i)
#pragma unroll
    for (int j = 0; j < 4; ++j) acc[i][j] = (fx4){0.f, 0.f, 0.f, 0.f};

  for (int kt = 0; kt < K; kt += 64) {
    __syncthreads();
#pragma unroll
    for (int it = 0; it < 4; ++it) {
      int ci = (it << 8) + t;
      int r = ci >> 3, cs = (ci & 7) ^ (r & 7);
      ushx8 va = ld8(A, aoff + (long)(m0 + r) * K + kt + (cs << 3), af);
      *(ushx8*)&sA[ci << 3] = va;
      ushx8 vb = ld8(Bm, (long)(n0 + r) * K + kt + (cs << 3), bfl);
      *(ushx8*)&sB[ci << 3] = vb;
    }
    __syncthreads();
#pragma unroll
    for (int s = 0; s < 2; ++s) {
      const int g = (s << 2) + lg;
      sx8 afr[4], bfr[4];
#pragma unroll
      for (int i = 0; i < 4; ++i) {
        int ra = wm + (i << 4) + lm;
        afr[i] = *(const sx8*)&sA[ra * 64 + ((g ^ (ra & 7)) << 3)];
        int rb = wn + (i << 4) + lm;
        bfr[i] = *(const sx8*)&sB[rb * 64 + ((g ^ (rb & 7)) << 3)];
      }
#pragma unroll
      for (int i = 0; i < 4; ++i)
#pragma unroll
        for (int j = 0; j < 4; ++j)
          acc[i][j] = __builtin_amdgcn_mfma_f32_16x16x32_bf16(afr[i], bfr[j], acc[i][j], 0, 0, 0);
    }
  }

#pragma unroll
  for (int j = 0; j < 4; ++j) {
    const int col = n0 + wn + (j << 4) + lm;
    float bv = 0.f;
    if (BIAS) bv = biasf ? ((const float*)bias)[col] : b2f(((const u16*)bias)[col]);
#pragma unroll
    for (int i = 0; i < 4; ++i) {
      const int row0 = m0 + wm + (i << 4) + (lg << 2);
#pragma unroll
      for (int r = 0; r < 4; ++r) {
        float v = acc[i][j][r] + bv;
        if (RELU) v = fmaxf(v, 0.f);
        C[(size_t)(row0 + r) * N + col] = f2b(v);
      }
    }
  }
}

// ---------------------------------------------------------------------------
__global__ __launch_bounds__(256)
void transpose_any(const void* __restrict__ in, u16* __restrict__ out,
                   int R, int C, const int* f_p) {
  __shared__ u16 tile[64][68];
  const bool f = (*f_p != 0);
  const int r0 = blockIdx.y << 6, c0 = blockIdx.x << 6;
  const int t = threadIdx.x;
#pragma unroll
  for (int it = 0; it < 4; ++it) {
    int j = (it << 8) + t;
    int rr = j >> 4, cc4 = (j & 15) << 2;
    float v[4];
    ld4f(in, (long)(r0 + rr) * C + c0 + cc4, f, v);
#pragma unroll
    for (int q = 0; q < 4; ++q) tile[rr][cc4 + q] = f2b(v[q]);
  }
  __syncthreads();
#pragma unroll
  for (int it = 0; it < 4; ++it) {
    int j = (it << 8) + t;
    int cc = j >> 4, rr4 = (j & 15) << 2;
    ushx4 v;
    v[0] = tile[rr4 + 0][cc]; v[1] = tile[rr4 + 1][cc];
    v[2] = tile[rr4 + 2][cc]; v[3] = tile[rr4 + 3][cc];
    *(ushx4*)&out[(size_t)(c0 + cc) * R + r0 + rr4] = v;
  }
}

// ---------------------------------------------------------------------------
// Flash attention, swapped-QK^T. grid.x = 512 (XCD-swizzled); grid.y = batch.
// Per wave 16 q rows; lane (lm,lg) owns softmax row q=lm for k=nt*16+lg*4+r.
// K/V reg-staged one k-tile ahead (T14). P goes through a wave-local
// XOR-swizzled LDS buffer (8 b64 writes + 4 b128 reads; no bpermute).
// Raw-domain softmax: max on raw scores, scale folded into exp FMA.
// LDS: sK 16K + sVt 17K + sP2 16K = 49K -> 3 blocks/CU.
// ---------------------------------------------------------------------------
__global__ __launch_bounds__(256, 3)
void attn_kernel(const u16* __restrict__ qp, const u16* __restrict__ kp,
                 const u16* __restrict__ vp, int lds_,
                 const int* __restrict__ mask, u16* __restrict__ ctx,
                 const int* __restrict__ mflag) {
  __shared__ __align__(16) u16 sK[128 * 64];
  __shared__ __align__(16) u16 sVt[64 * 136];
  __shared__ __align__(16) unsigned sP2[4][1024];

  const bool nomask = (*mflag != 0);
  const long boff = (long)blockIdx.y * SEQ * (long)lds_;
  qp += boff; kp += boff; vp += boff;
  mask += (size_t)blockIdx.y * ((size_t)SEQ * SEQ);
  ctx += (size_t)blockIdx.y * ((size_t)SEQ * DM);

  const int id = (blockIdx.x & 7) * ((int)gridDim.x >> 3) + (blockIdx.x >> 3);
  const int q0 = (id & 31) << 6;
  const int h  = id >> 5;
  const int t = threadIdx.x, lane = t & 63, w = t >> 6;
  const int hoff = h << 6;
  const int lm = lane & 15, lg = lane >> 4;
  const int myq = q0 + (w << 4) + lm;        // this lane's softmax row
  const int aslot = 20 * lg;                  // shfl src: lane lg*16 + (lg*4+r)

  // staging geometry
  const int csK = (t & 7) ^ ((t >> 3) & 7);   // K col-octet (swizzled)
  const int kq = (t & 31) << 2, dg = (t >> 5) << 3;
  const int vcol = kq ^ (((t >> 5) & 1) << 3);   // sVt write col (row-swizzled)
  unsigned* pw = &sP2[w][0];
  const int wswz = (lm & 7) << 2;
  const int pwb = lm << 6;
  const int vrs = ((lm >> 3) & 1) << 3;       // sVt read col swizzle

  // Q fragments: row myq, octets lg and 4+lg
  sx8 aq[2];
#pragma unroll
  for (int s = 0; s < 2; ++s)
    aq[s] = *(const sx8*)&qp[(size_t)myq * lds_ + hoff + (((s << 2) + lg) << 3)];

  fx4 o[4];
#pragma unroll
  for (int i = 0; i < 4; ++i) o[i] = (fx4){0.f, 0.f, 0.f, 0.f};
  float m_prev = -1e30f, lsum = 0.f;
  const float SCL = 0.18033688f;    // 0.125 * log2(e)
  const float RTHR = 44.36142f;     // 8 / SCL (defer-max bound, raw domain)

  auto loadK = [&](int kt, uint4* kr) {
    const int k0 = kt << 7;
#pragma unroll
    for (int it = 0; it < 4; ++it) {
      int r = (it << 5) + (t >> 3);
      kr[it] = *(const uint4*)&kp[(size_t)(k0 + r) * lds_ + hoff + (csK << 3)];
    }
  };
  auto loadV = [&](int kt, uint4* vr) {
    const int k0 = kt << 7;
#pragma unroll
    for (int i = 0; i < 4; ++i)
      vr[i] = *(const uint4*)&vp[(size_t)(k0 + kq + i) * lds_ + hoff + dg];
  };
  auto writeStage = [&](const uint4* kr, const uint4* vr) {
#pragma unroll
    for (int it = 0; it < 4; ++it) {
      int ci = (it << 8) + t;
      *(uint4*)&sK[ci << 3] = kr[it];
    }
    const unsigned A0[4] = {vr[0].x, vr[0].y, vr[0].z, vr[0].w};
    const unsigned B0[4] = {vr[1].x, vr[1].y, vr[1].z, vr[1].w};
    const unsigned C0[4] = {vr[2].x, vr[2].y, vr[2].z, vr[2].w};
    const unsigned D0[4] = {vr[3].x, vr[3].y, vr[3].z, vr[3].w};
#pragma unroll
    for (int j = 0; j < 8; ++j) {
      const unsigned sel = (j & 1) ? 0x07060302u : 0x05040100u;
      ux2 wv;
      wv[0] = __builtin_amdgcn_perm(B0[j >> 1], A0[j >> 1], sel);
      wv[1] = __builtin_amdgcn_perm(D0[j >> 1], C0[j >> 1], sel);
      *(ux2*)&sVt[(size_t)(dg + j) * 136 + vcol] = wv;
    }
  };

  auto computeTile = [&](int kt) {
    const int k0 = kt << 7;
    // QK^T swapped: lane holds S[q=lm][k=nt*16+lg*4+r] (raw scores)
    fx4 sc[8];
#pragma unroll
    for (int nt = 0; nt < 8; ++nt) sc[nt] = (fx4){0.f, 0.f, 0.f, 0.f};
    __builtin_amdgcn_s_setprio(1);
#pragma unroll
    for (int s = 0; s < 2; ++s) {
      const int g = (s << 2) + lg;
#pragma unroll
      for (int nt = 0; nt < 8; ++nt) {
        int rk = (nt << 4) + lm;
        sx8 bk = *(const sx8*)&sK[rk * 64 + ((g ^ (rk & 7)) << 3)];
        sc[nt] = __builtin_amdgcn_mfma_f32_16x16x32_bf16(bk, aq[s], sc[nt], 0, 0, 0);
      }
    }
    __builtin_amdgcn_s_setprio(0);

    if (!nomask) {
#pragma unroll
      for (int nt = 0; nt < 8; ++nt)
#pragma unroll
        for (int r = 0; r < 4; ++r) {
          const int col = k0 + (nt << 4) + (lg << 2) + r;
          if (mask[((size_t)myq << 11) + col] == 0) sc[nt][r] = -1e9f;
        }
    }

    float tm = sc[0][0];
#pragma unroll
    for (int nt = 0; nt < 8; ++nt)
#pragma unroll
      for (int r = 0; r < 4; ++r) tm = fmaxf(tm, sc[nt][r]);
    tm = fmaxf(tm, __shfl_xor(tm, 16));
    tm = fmaxf(tm, __shfl_xor(tm, 32));

    if (!__all(tm <= m_prev + RTHR)) {     // defer-max: rescale rarely
      const float mn = fmaxf(m_prev, tm);
      const float alpha = fexp2((m_prev - mn) * SCL);
      lsum *= alpha;
#pragma unroll
      for (int r = 0; r < 4; ++r) {
        float ar = __shfl(alpha, aslot + r);
#pragma unroll
        for (int ot = 0; ot < 4; ++ot) o[ot][r] *= ar;
      }
      m_prev = mn;
    }

    const float msc = m_prev * SCL;
    float rs = 0.f;
    float pvv[8][4];
#pragma unroll
    for (int nt = 0; nt < 8; ++nt)
#pragma unroll
      for (int r = 0; r < 4; ++r) {
        float e = fexp2(__builtin_fmaf(sc[nt][r], SCL, -msc));
        pvv[nt][r] = e;
        rs += e;
      }
    rs += __shfl_xor(rs, 16);
    rs += __shfl_xor(rs, 32);
    lsum += rs;

    // P -> bf16 pairs, wave-local swizzled LDS
    unsigned cpk[8][2];
#pragma unroll
    for (int nt = 0; nt < 8; ++nt) {
      asm("v_cvt_pk_bf16_f32 %0, %1, %2" : "=v"(cpk[nt][0]) : "v"(pvv[nt][0]), "v"(pvv[nt][1]));
      asm("v_cvt_pk_bf16_f32 %0, %1, %2" : "=v"(cpk[nt][1]) : "v"(pvv[nt][2]), "v"(pvv[nt][3]));
    }
#pragma unroll
    for (int nt = 0; nt < 8; ++nt)
      *(ux2*)&pw[pwb + (((nt << 3) + (lg << 1)) ^ wswz)] = (ux2){cpk[nt][0], cpk[nt][1]};

    // PV: A-frag = P[q=lm][k=ks*32+lg*8+e] from sP2; B = sVt
    __builtin_amdgcn_s_setprio(1);
#pragma unroll
    for (int ks = 0; ks < 4; ++ks) {
      sx8 ap = *(const sx8*)&pw[pwb + (((ks << 4) + (lg << 2)) ^ wswz)];
#pragma unroll
      for (int ot = 0; ot < 4; ++ot) {
        int d = (ot << 4) + lm;
        sx8 bv = *(const sx8*)&sVt[d * 136 + (((ks << 5) + (lg << 3)) ^ vrs)];
        o[ot] = __builtin_amdgcn_mfma_f32_16x16x32_bf16(ap, bv, o[ot], 0, 0, 0);
      }
    }
    __builtin_amdgcn_s_setprio(0);
  };

  uint4 krA[4], vrA[4], krB[4], vrB[4];
  loadK(0, krA); loadV(0, vrA);
  for (int kt = 0; kt < 16; kt += 2) {
    __syncthreads();
    writeStage(krA, vrA);
    loadK(kt + 1, krB); loadV(kt + 1, vrB);
    __syncthreads();
    computeTile(kt);
    __syncthreads();
    writeStage(krB, vrB);
    if (kt + 2 < 16) { loadK(kt + 2, krA); loadV(kt + 2, vrA); }
    __syncthreads();
    computeTile(kt + 1);
  }

  float inv = (lsum > 0.f) ? 1.f / lsum : 0.f;
#pragma unroll
  for (int r = 0; r < 4; ++r) {
    float ir = __shfl(inv, aslot + r);
#pragma unroll
    for (int ot = 0; ot < 4; ++ot) {
      const int rowg = q0 + (w << 4) + (lg << 2) + r;
      const int col = hoff + (ot << 4) + lm;
      ctx[((size_t)rowg << 10) + col] = f2b(o[ot][r] * ir);
    }
  }
}

// ---------------------------------------------------------------------------
__global__ __launch_bounds__(256)
void ln_dual(const u16* __restrict__ a, const void* __restrict__ res, long roff,
             const void* __restrict__ g1, const void* __restrict__ b1,
             const void* __restrict__ gf, const void* __restrict__ bf,
             u16* __restrict__ xo, u16* __restrict__ xlo, const int* f_p) {
  __shared__ float red[8];
  const bool f = (*f_p != 0);
  const int row = blockIdx.x, t = threadIdx.x;
  const int lane = t & 63, w = t >> 6;
  const size_t base = (size_t)row << 10;
  const int c = t << 2;

  ushx4 a4 = *(const ushx4*)(a + base + c);
  float rv[4];
  ld4f(res, roff + (long)base + c, f, rv);
  float v[4], s = 0.f, ss = 0.f;
#pragma unroll
  for (int j = 0; j < 4; ++j) { v[j] = b2f(a4[j]) + rv[j]; s += v[j]; ss += v[j] * v[j]; }
#pragma unroll
  for (int off = 32; off > 0; off >>= 1) { s += __shfl_xor(s, off); ss += __shfl_xor(ss, off); }
  if (lane == 0) { red[w] = s; red[4 + w] = ss; }
  __syncthreads();
  s = red[0] + red[1] + red[2] + red[3];
  ss = red[4] + red[5] + red[6] + red[7];
  float mu = s * (1.f / 1024.f);
  float rstd = rsqrtf(fmaxf(ss * (1.f / 1024.f) - mu * mu, 0.f) + 1e-5f);

  float g4[4], b4[4];
  ld4f(g1, c, f, g4); ld4f(b1, c, f, b4);
  float x[4], s2 = 0.f, ss2 = 0.f;
  ushx4 xo4;
#pragma unroll
  for (int j = 0; j < 4; ++j) {
    x[j] = (v[j] - mu) * rstd * g4[j] + b4[j];
    xo4[j] = f2b(x[j]);
    s2 += x[j]; ss2 += x[j] * x[j];
  }
  *(ushx4*)(xo + base + c) = xo4;
#pragma unroll
  for (int off = 32; off > 0; off >>= 1) { s2 += __shfl_xor(s2, off); ss2 += __shfl_xor(ss2, off); }
  __syncthreads();
  if (lane == 0) { red[w] = s2; red[4 + w] = ss2; }
  __syncthreads();
  s2 = red[0] + red[1] + red[2] + red[3];
  ss2 = red[4] + red[5] + red[6] + red[7];
  float mu2 = s2 * (1.f / 1024.f);
  float rstd2 = rsqrtf(fmaxf(ss2 * (1.f / 1024.f) - mu2 * mu2, 0.f) + 1e-5f);

  ld4f(gf, c, f, g4); ld4f(bf, c, f, b4);
  ushx4 xl4;
#pragma unroll
  for (int j = 0; j < 4; ++j)
    xl4[j] = f2b((x[j] - mu2) * rstd2 * g4[j] + b4[j]);
  *(ushx4*)(xlo + base + c) = xl4;
}

// ---------------------------------------------------------------------------
__global__ __launch_bounds__(256)
void ln_final(const u16* __restrict__ a, const u16* __restrict__ resx,
              const void* __restrict__ g, const void* __restrict__ bb,
              void* __restrict__ out, long ooff, const int* f_p) {
  __shared__ float red[8];
  const bool f = (*f_p != 0);
  const int row = blockIdx.x, t = threadIdx.x;
  const int lane = t & 63, w = t >> 6;
  const size_t base = (size_t)row << 10;
  const int c = t << 2;

  ushx4 a4 = *(const ushx4*)(a + base + c);
  ushx4 r4 = *(const ushx4*)(resx + base + c);
  float v[4], s = 0.f, ss = 0.f;
#pragma unroll
  for (int j = 0; j < 4; ++j) { v[j] = b2f(a4[j]) + b2f(r4[j]); s += v[j]; ss += v[j] * v[j]; }
#pragma unroll
  for (int off = 32; off > 0; off >>= 1) { s += __shfl_xor(s, off); ss += __shfl_xor(ss, off); }
  if (lane == 0) { red[w] = s; red[4 + w] = ss; }
  __syncthreads();
  s = red[0] + red[1] + red[2] + red[3];
  ss = red[4] + red[5] + red[6] + red[7];
  float mu = s * (1.f / 1024.f);
  float rstd = rsqrtf(fmaxf(ss * (1.f / 1024.f) - mu * mu, 0.f) + 1e-5f);

  float g4[4], b4[4];
  ld4f(g, c, f, g4); ld4f(bb, c, f, b4);
  if (f) {
    fx4 o4;
#pragma unroll
    for (int j = 0; j < 4; ++j) o4[j] = (v[j] - mu) * rstd * g4[j] + b4[j];
    *(fx4*)((float*)out + ooff + base + c) = o4;
  } else {
    ushx4 o4;
#pragma unroll
    for (int j = 0; j < 4; ++j) o4[j] = f2b((v[j] - mu) * rstd * g4[j] + b4[j]);
    *(ushx4*)((u16*)out + ooff + base + c) = o4;
  }
}

// ---------------------------------------------------------------------------
extern "C" void kernel_launch(void* const* d_in, const int* in_sizes, int n_in,
                              void* d_out, int out_size, void* d_ws, size_t ws_size,
                              hipStream_t stream) {
  (void)in_sizes; (void)n_in; (void)out_size;
  const void* query = d_in[0];
  const void* keyi  = d_in[1];
  const void* value = d_in[2];
  const int*  mask  = (const int*)d_in[3];
  const void* Wq = d_in[4];
  const void* Wk = d_in[5];
  const void* Wv = d_in[6];
  const void* Wo = d_in[7];
  const void* bo = d_in[8];
  const void* g1 = d_in[9];
  const void* b1 = d_in[10];
  const void* g2 = d_in[11];
  const void* b2 = d_in[12];
  const void* gff = d_in[13];
  const void* bff = d_in[14];
  const void* W1 = d_in[15];
  const void* bf1 = d_in[16];
  const void* W2 = d_in[17];
  const void* bf2 = d_in[18];

  char* p = (char*)d_ws;
  int* flags = (int*)p;
  const int* F = flags;
  const int* Z = flags + 1;
  const int* M = flags + 2;
  dim3 blk(256);

  // footprint(CH) = 4096 + 24MiB (packed weights) + 7*CH*2048 bytes
  const size_t FIXED = 4096 + ((size_t)24 << 20);
  const size_t needC = FIXED + (size_t)8192 * 14336;   // ~142.6 MB
  const size_t needA = FIXED + (size_t)4096 * 14336;   // ~80.0 MB
  const size_t needB = FIXED + (size_t)2048 * 14336;   // ~52.0 MB

  if (ws_size >= needB) {
    // ------------------------- NEW PATH -------------------------
    const int CH = (ws_size >= needC) ? 8192 : (ws_size >= needA) ? 4096 : 2048;
    const int nch = 8192 / CH;

    u16* Wqkv  = (u16*)(p + 4096);                       // [3*1024,1024]
    u16* Wo_bf = Wqkv + (size_t)3 * DM * DM;             // [1024,1024]
    u16* W1T   = Wo_bf + (size_t)DM * DM;                // [4096,1024]
    u16* W2T   = W1T + (size_t)DFF * DM;                 // [1024,4096]
    u16* D0    = W2T + (size_t)DM * DFF;                 // in_bf / h
    u16* D1    = D0 + (size_t)3 * CH * DM;               // qkv / ao,x,xln
    u16* D2    = D1 + (size_t)3 * CH * DM;               // ctx / ff
    u16* qb = D0;
    u16* qkv = D1;
    u16* ao = D1, *x = D1 + (size_t)CH * DM, *xln = D1 + (size_t)2 * CH * DM;
    u16* h = D0;                                         // CH*4096 elems
    u16* ctx = D2, *ff = D2;

    detect_kernel<<<1, 64, 0, stream>>>(query, flags);
    mask_scan<<<dim3(8192), blk, 0, stream>>>(mask, flags);
    pack_w<<<dim3(2048), blk, 0, stream>>>(Wq, Wk, Wv, Wo, Wqkv, Wo_bf, F);
    transpose_any<<<dim3(DFF / 64, DM / 64), blk, 0, stream>>>(W1, W1T, DM, DFF, F);
    transpose_any<<<dim3(DM / 64, DFF / 64), blk, 0, stream>>>(W2, W2T, DFF, DM, F);

    for (int c = 0; c < nch; ++c) {
      const long off = (long)c * CH * DM;
      const long n = (long)CH * DM;
      conv_bf3<<<dim3((int)(n >> 11), 3), blk, 0, stream>>>(query, keyi, value, off, qb, n, F);

      // q/k/v projections co-dispatched: z in {0,1,2}
      gemm_bb<false, false, false><<<dim3((CH / 128) * 8, 3), blk, 0, stream>>>(
          qb, (long)CH * DM, Wqkv, (long)DM * DM, nullptr,
          qkv, 1024L, CH, DM, DM, 3072, Z);

      const int bpc = CH / SEQ, b0 = c * bpc;
      attn_kernel<<<dim3(512, bpc), blk, 0, stream>>>(
          qkv, qkv + 1024, qkv + 2048, 3072,
          mask + (size_t)b0 * SEQ * SEQ, ctx, M);

      gemm_bb<false, true, true><<<dim3((CH / 128) * 8, 1), blk, 0, stream>>>(
          ctx, 0, Wo_bf, 0, bo, ao, 0, CH, DM, DM, DM, F);

      ln_dual<<<dim3(CH), blk, 0, stream>>>(ao, query, off, g1, b1, gff, bff, x, xln, F);

      gemm_bb<true, true, false><<<dim3((CH / 128) * 32, 1), blk, 0, stream>>>(
          xln, 0, W1T, 0, bf1, h, 0, CH, DFF, DM, DFF, F);
      gemm_bb<false, true, true><<<dim3((CH / 128) * 8, 1), blk, 0, stream>>>(
          h, 0, W2T, 0, bf2, ff, 0, CH, DM, DFF, DM, F);

      ln_final<<<dim3(CH), blk, 0, stream>>>(ff, x, g2, b2, d_out, off, F);
    }
  } else {
    // ------------------------- LEGACY PATH (round-3 proven) -------------------------
    const int CH = 2048, FH = 1024;
    const int nch = 8192 / CH;
    const size_t h0 = 4096;
    u16* W1T = (u16*)(p + h0);
    u16* W2T = W1T + (size_t)DFF * DM;
    u16* hb  = (u16*)(p + h0 + ((size_t)16 << 20));
    const size_t HB = (size_t)FH * DFF * 2;
    u16* r0 = (u16*)(p + h0 + ((size_t)16 << 20) + HB);
    const size_t CE = (size_t)CH * DM;
    u16* qp = r0;
    u16* kp = qp + CE;
    u16* vp = kp + CE;
    u16* ctxb = vp + CE;
    u16* x = qp; u16* xln = kp; u16* ao = vp; u16* ff = ctxb;

    detect_kernel<<<1, 64, 0, stream>>>(query, flags);
    mask_scan<<<dim3(8192), blk, 0, stream>>>(mask, flags);
    transpose_any<<<dim3(DFF / 64, DM / 64), blk, 0, stream>>>(W1, W1T, DM, DFF, F);
    transpose_any<<<dim3(DM / 64, DFF / 64), blk, 0, stream>>>(W2, W2T, DFF, DM, F);

    for (int c = 0; c < nch; ++c) {
      const long off = (long)c * CH * DM;
      dim3 gq((CH / 128) * (DM / 128));

      gemm_nt<false, false><<<gq, blk, 0, stream>>>(query, off, Wq, Wq, qp, CH, DM, DM, F, F, Z);
      gemm_nt<false, false><<<gq, blk, 0, stream>>>(keyi,  off, Wk, Wk, kp, CH, DM, DM, F, F, Z);
      gemm_nt<false, false><<<gq, blk, 0, stream>>>(value, off, Wv, Wv, vp, CH, DM, DM, F, F, Z);

      const int bpc = CH / SEQ, b0 = c * bpc;
      for (int bl = 0; bl < bpc; ++bl) {
        const size_t lo = (size_t)bl * SEQ * DM;
        attn_kernel<<<dim3(512, 1), blk, 0, stream>>>(
            qp + lo, kp + lo, vp + lo, 1024,
            mask + (size_t)(b0 + bl) * SEQ * SEQ, ctxb + lo, M);
      }

      gemm_nt<false, true><<<gq, blk, 0, stream>>>(ctxb, 0, Wo, bo, ao, CH, DM, DM, Z, F, F);

      ln_dual<<<dim3(CH), blk, 0, stream>>>(ao, query, off, g1, b1, gff, bff, x, xln, F);

      for (int qs = 0; qs < CH / FH; ++qs) {
        const long so = (long)qs * FH * DM;
        gemm_nt<true, true><<<dim3((FH / 128) * (DFF / 128)), blk, 0, stream>>>(
            xln + so, 0, W1T, bf1, hb, FH, DFF, DM, Z, Z, F);
        gemm_nt<false, true><<<dim3((FH / 128) * (DM / 128)), blk, 0, stream>>>(
            hb, 0, W2T, bf2, ff + so, FH, DM, DFF, Z, Z, F);
      }

      ln_final<<<dim3(CH), blk, 0, stream>>>(ff, x, g2, b2, d_out, off, F);
    }
  }
}

// Round 4
// 711.680 us; speedup vs baseline: 1.3238x; 1.1671x over previous
//
#include <hip/hip_runtime.h>

// ---------------------------------------------------------------------------
// SublayerConnection: MHA + residual/LN + FF + residual/LN
// B=4 S=2048 D=1024 H=16 Dk=64 Dff=4096.
// Round 8: fix round-7 scratch regression (rule #20: staging arrays through
// lambda pointers -> private memory, 468MB scratch writes/dispatch). K goes
// back to global_load_lds (0 VGPR); V prefetch = 4 NAMED uint4 regs, issued
// after the barrier so vmcnt(0) drain doesn't serialize them. Compute path
// (sP2 wave-local P, raw-domain softmax, defer-max, setprio) kept verbatim
// (verified round 7). GEMMs/LN/launcher unchanged.
// ---------------------------------------------------------------------------

#define DM   1024
#define DFF  4096
#define SEQ  2048

typedef unsigned short u16;
typedef short          sx8  __attribute__((ext_vector_type(8)));
typedef unsigned short ushx8 __attribute__((ext_vector_type(8)));
typedef unsigned short ushx4 __attribute__((ext_vector_type(4)));
typedef float          fx4  __attribute__((ext_vector_type(4)));
typedef unsigned int   ux2  __attribute__((ext_vector_type(2)));

__device__ __forceinline__ void async16(const void* g, void* l) {
  __builtin_amdgcn_global_load_lds((__attribute__((address_space(1))) void*)g,
                                   (__attribute__((address_space(3))) void*)l,
                                   16, 0, 0);
}
__device__ __forceinline__ float b2f(u16 u) {
  union { unsigned int i; float f; } v; v.i = ((unsigned int)u) << 16; return v.f;
}
__device__ __forceinline__ u16 f2b(float f) {
  union { float f; unsigned int i; } v; v.f = f;
  unsigned int r = v.i + 0x7fffu + ((v.i >> 16) & 1u);
  return (u16)(r >> 16);
}
__device__ __forceinline__ float fexp2(float x) {
#if __has_builtin(__builtin_amdgcn_exp2f)
  return __builtin_amdgcn_exp2f(x);
#else
  return exp2f(x);
#endif
}
__device__ __forceinline__ ushx8 ld8(const void* p, long idx, bool f32) {
  if (f32) {
    const float* s = (const float*)p + idx;
    fx4 a = *(const fx4*)s, b = *(const fx4*)(s + 4);
    ushx8 r;
    r[0] = f2b(a[0]); r[1] = f2b(a[1]); r[2] = f2b(a[2]); r[3] = f2b(a[3]);
    r[4] = f2b(b[0]); r[5] = f2b(b[1]); r[6] = f2b(b[2]); r[7] = f2b(b[3]);
    return r;
  }
  return *(const ushx8*)((const u16*)p + idx);
}
__device__ __forceinline__ void ld4f(const void* p, long idx, bool f32, float* o) {
  if (f32) {
    fx4 a = *(const fx4*)((const float*)p + idx);
    o[0] = a[0]; o[1] = a[1]; o[2] = a[2]; o[3] = a[3];
  } else {
    ushx4 a = *(const ushx4*)((const u16*)p + idx);
    o[0] = b2f(a[0]); o[1] = b2f(a[1]); o[2] = b2f(a[2]); o[3] = b2f(a[3]);
  }
}

// ---------------------------------------------------------------------------
__global__ void detect_kernel(const void* q, int* flags) {
  int lane = threadIdx.x;
  u16 v = ((const u16*)q)[lane << 1];
  int e = (v >> 7) & 0xff;
  int pl = (e >= 0x60 && e <= 0x8c) ? 1 : 0;
  unsigned long long m = __ballot(pl);
  if (lane == 0) { flags[0] = (__popcll(m) >= 40) ? 0 : 1; flags[1] = 0; flags[2] = 1; }
}

// Scan mask for any zero; flags[2] stays 1 iff every element nonzero.
__global__ __launch_bounds__(256)
void mask_scan(const int* __restrict__ m, int* flags) {
  long i = (((long)blockIdx.x << 8) + threadIdx.x) << 3;
  const int4 a = *(const int4*)(m + i);
  const int4 b = *(const int4*)(m + i + 4);
  bool ok = a.x && a.y && a.z && a.w && b.x && b.y && b.z && b.w;
  if (!__all(ok)) { if ((threadIdx.x & 63) == 0) flags[2] = 0; }
}

// Pack Wq/Wk/Wv -> Wqkv [3*1024,1024] bf16 and Wo -> bf16.
__global__ __launch_bounds__(256)
void pack_w(const void* Wq, const void* Wk, const void* Wv, const void* Wo,
            u16* Wqkv, u16* Wo_bf, const int* f_p) {
  const bool f = (*f_p != 0);
  long i = (((long)blockIdx.x << 8) + threadIdx.x) << 3;
  const long QKVN = (long)3 * DM * DM;
  if (i < QKVN) {
    int row = (int)(i >> 10);
    const void* src = (row < DM) ? Wq : (row < 2 * DM ? Wk : Wv);
    long s = ((long)(row & (DM - 1)) << 10) + (i & 1023);
    *(ushx8*)(Wqkv + i) = ld8(src, s, f);
  } else {
    long j = i - QKVN;
    *(ushx8*)(Wo_bf + j) = ld8(Wo, j, f);
  }
}

// Convert q/k/v chunk to bf16; grid.y selects source, dst stride n.
__global__ __launch_bounds__(256)
void conv_bf3(const void* q, const void* k, const void* v, long off,
              u16* dst, long n, const int* f_p) {
  const bool f = (*f_p != 0);
  const void* src = (blockIdx.y == 0) ? q : (blockIdx.y == 1 ? k : v);
  long i = (((long)blockIdx.x << 8) + threadIdx.x) << 3;
  if (i < n) *(ushx8*)(dst + (long)blockIdx.y * n + i) = ld8(src, off + i, f);
}

// ---------------------------------------------------------------------------
// Pure-bf16 NT GEMM with global_load_lds(16B) staging. C=A@B^T (+bias)(+relu).
// grid.y = z selects (A,B,C) via element strides az/bz/cz. C row stride ldc.
// DBUF: 3 LDS buffers, prefetch depth 2, counted vmcnt(16) so two tiles of
// loads stay in flight across barriers (T3/T4). For 1-2 block/CU grids.
// All grids are %8==0 -> bijective XCD swizzle for L2 A-tile sharing.
// ---------------------------------------------------------------------------
template<bool RELU, bool BIAS, bool DBUF>
__global__ __launch_bounds__(256)
void gemm_bb(const u16* __restrict__ A, long az, const u16* __restrict__ B, long bz,
             const void* __restrict__ bias, u16* __restrict__ C, long cz,
             int M, int N, int K, int ldc, const int* biasf_p) {
  __shared__ __align__(16) u16 sA[(DBUF ? 3 : 1) * 128 * 64];
  __shared__ __align__(16) u16 sB[(DBUF ? 3 : 1) * 128 * 64];
  const int z = blockIdx.y;
  A += (long)z * az; B += (long)z * bz; C += (long)z * cz;
  const bool biasf = BIAS && (*biasf_p != 0);
  const int t = threadIdx.x;
  const int lane = t & 63, w = t >> 6;
  const int lm = lane & 15, lg = lane >> 4;
  const int ntil = N >> 7;
  // XCD-aware bijective swizzle (gridDim.x % 8 == 0 for all dispatches)
  const int bx = (blockIdx.x & 7) * ((int)gridDim.x >> 3) + (blockIdx.x >> 3);
  const int m0 = (bx / ntil) << 7;
  const int n0 = (bx % ntil) << 7;
  const int wm = (w & 1) << 6, wn = (w >> 1) << 6;

  fx4 acc[4][4];
#pragma unroll
  for (int i = 0; i < 4; ++i)
#pragma unroll
    for (int j = 0; j < 4; ++j) acc[i][j] = (fx4){0.f, 0.f, 0.f, 0.f};

  auto stage = [&](int so, int kt) {
#pragma unroll
    for (int it = 0; it < 4; ++it) {
      int ci = (it << 8) + t;
      int r = ci >> 3, cs = (ci & 7) ^ (r & 7);
      async16(&A[(size_t)(m0 + r) * K + kt + (cs << 3)], &sA[so + (ci << 3)]);
    }
#pragma unroll
    for (int it = 0; it < 4; ++it) {
      int ci = (it << 8) + t;
      int r = ci >> 3, cs = (ci & 7) ^ (r & 7);
      async16(&B[(size_t)(n0 + r) * K + kt + (cs << 3)], &sB[so + (ci << 3)]);
    }
  };

  auto compute = [&](int so) {
#pragma unroll
    for (int s = 0; s < 2; ++s) {
      const int g = (s << 2) + lg;
      sx8 afr[4], bfr[4];
#pragma unroll
      for (int i = 0; i < 4; ++i) {
        int ra = wm + (i << 4) + lm;
        afr[i] = *(const sx8*)&sA[so + ra * 64 + ((g ^ (ra & 7)) << 3)];
        int rb = wn + (i << 4) + lm;
        bfr[i] = *(const sx8*)&sB[so + rb * 64 + ((g ^ (rb & 7)) << 3)];
      }
      __builtin_amdgcn_s_setprio(1);
#pragma unroll
      for (int i = 0; i < 4; ++i)
#pragma unroll
        for (int j = 0; j < 4; ++j)
          acc[i][j] = __builtin_amdgcn_mfma_f32_16x16x32_bf16(afr[i], bfr[j], acc[i][j], 0, 0, 0);
      __builtin_amdgcn_s_setprio(0);
    }
  };

  if (DBUF) {
    const int NT = K >> 6;
    stage(0, 0);
    if (NT > 1) stage(8192, 64);
    for (int n = 0; n < NT; ++n) {
      __builtin_amdgcn_s_barrier();
      if (n + 2 < NT) {
        stage(((n + 2) % 3) << 13, (n + 2) << 6);
        asm volatile("s_waitcnt vmcnt(16)" ::: "memory");
      } else if (n + 1 < NT) {
        asm volatile("s_waitcnt vmcnt(8)" ::: "memory");
      } else {
        asm volatile("s_waitcnt vmcnt(0)" ::: "memory");
      }
      __builtin_amdgcn_sched_barrier(0);
      compute((n % 3) << 13);
    }
  } else {
    for (int kt = 0; kt < K; kt += 64) {
      __syncthreads();
      stage(0, kt);
      __syncthreads();
      compute(0);
    }
  }

#pragma unroll
  for (int j = 0; j < 4; ++j) {
    const int col = n0 + wn + (j << 4) + lm;
    float bv = 0.f;
    if (BIAS) bv = biasf ? ((const float*)bias)[col] : b2f(((const u16*)bias)[col]);
#pragma unroll
    for (int i = 0; i < 4; ++i) {
      const int row0 = m0 + wm + (i << 4) + (lg << 2);
#pragma unroll
      for (int r = 0; r < 4; ++r) {
        float v = acc[i][j][r] + bv;
        if (RELU) v = fmaxf(v, 0.f);
        C[(size_t)(row0 + r) * ldc + col] = f2b(v);
      }
    }
  }
}

// ---------------------------------------------------------------------------
// Flag-dtype NT GEMM (legacy path, proven in round 3).
// ---------------------------------------------------------------------------
template<bool RELU, bool BIAS>
__global__ __launch_bounds__(256)
void gemm_nt(const void* __restrict__ A, long aoff, const void* __restrict__ Bm,
             const void* __restrict__ bias, u16* __restrict__ C,
             int M, int N, int K,
             const int* af_p, const int* bf_p, const int* biasf_p) {
  __shared__ __align__(16) u16 sA[128 * 64];
  __shared__ __align__(16) u16 sB[128 * 64];
  const bool af = (*af_p != 0), bfl = (*bf_p != 0), biasf = (*biasf_p != 0);
  const int t = threadIdx.x;
  const int lane = t & 63, w = t >> 6;
  const int lm = lane & 15, lg = lane >> 4;
  const int ntil = N >> 7;
  const int m0 = (blockIdx.x / ntil) << 7;
  const int n0 = (blockIdx.x % ntil) << 7;
  const int wm = (w & 1) << 6, wn = (w >> 1) << 6;

  fx4 acc[4][4];
#pragma unroll
  for (int i = 0; i < 4; ++i)
#pragma unroll
    for (int j = 0; j < 4; ++j) acc[i][j] = (fx4){0.f, 0.f, 0.f, 0.f};

  for (int kt = 0; kt < K; kt += 64) {
    __syncthreads();
#pragma unroll
    for (int it = 0; it < 4; ++it) {
      int ci = (it << 8) + t;
      int r = ci >> 3, cs = (ci & 7) ^ (r & 7);
      ushx8 va = ld8(A, aoff + (long)(m0 + r) * K + kt + (cs << 3), af);
      *(ushx8*)&sA[ci << 3] = va;
      ushx8 vb = ld8(Bm, (long)(n0 + r) * K + kt + (cs << 3), bfl);
      *(ushx8*)&sB[ci << 3] = vb;
    }
    __syncthreads();
#pragma unroll
    for (int s = 0; s < 2; ++s) {
      const int g = (s << 2) + lg;
      sx8 afr[4], bfr[4];
#pragma unroll
      for (int i = 0; i < 4; ++i) {
        int ra = wm + (i << 4) + lm;
        afr[i] = *(const sx8*)&sA[ra * 64 + ((g ^ (ra & 7)) << 3)];
        int rb = wn + (i << 4) + lm;
        bfr[i] = *(const sx8*)&sB[rb * 64 + ((g ^ (rb & 7)) << 3)];
      }
#pragma unroll
      for (int i = 0; i < 4; ++i)
#pragma unroll
        for (int j = 0; j < 4; ++j)
          acc[i][j] = __builtin_amdgcn_mfma_f32_16x16x32_bf16(afr[i], bfr[j], acc[i][j], 0, 0, 0);
    }
  }

#pragma unroll
  for (int j = 0; j < 4; ++j) {
    const int col = n0 + wn + (j << 4) + lm;
    float bv = 0.f;
    if (BIAS) bv = biasf ? ((const float*)bias)[col] : b2f(((const u16*)bias)[col]);
#pragma unroll
    for (int i = 0; i < 4; ++i) {
      const int row0 = m0 + wm + (i << 4) + (lg << 2);
#pragma unroll
      for (int r = 0; r < 4; ++r) {
        float v = acc[i][j][r] + bv;
        if (RELU) v = fmaxf(v, 0.f);
        C[(size_t)(row0 + r) * N + col] = f2b(v);
      }
    }
  }
}

// ---------------------------------------------------------------------------
__global__ __launch_bounds__(256)
void transpose_any(const void* __restrict__ in, u16* __restrict__ out,
                   int R, int C, const int* f_p) {
  __shared__ u16 tile[64][68];
  const bool f = (*f_p != 0);
  const int r0 = blockIdx.y << 6, c0 = blockIdx.x << 6;
  const int t = threadIdx.x;
#pragma unroll
  for (int it = 0; it < 4; ++it) {
    int j = (it << 8) + t;
    int rr = j >> 4, cc4 = (j & 15) << 2;
    float v[4];
    ld4f(in, (long)(r0 + rr) * C + c0 + cc4, f, v);
#pragma unroll
    for (int q = 0; q < 4; ++q) tile[rr][cc4 + q] = f2b(v[q]);
  }
  __syncthreads();
#pragma unroll
  for (int it = 0; it < 4; ++it) {
    int j = (it << 8) + t;
    int cc = j >> 4, rr4 = (j & 15) << 2;
    ushx4 v;
    v[0] = tile[rr4 + 0][cc]; v[1] = tile[rr4 + 1][cc];
    v[2] = tile[rr4 + 2][cc]; v[3] = tile[rr4 + 3][cc];
    *(ushx4*)&out[(size_t)(c0 + cc) * R + r0 + rr4] = v;
  }
}

// ---------------------------------------------------------------------------
// Flash attention, swapped-QK^T. grid.x = 512 (XCD-swizzled); grid.y = batch.
// Per wave 16 q rows; lane (lm,lg) owns softmax row q=lm for k=nt*16+lg*4+r.
// K staged via global_load_lds (0 VGPR). V prefetched one tile ahead in 4
// NAMED uint4 regs (no arrays -> no scratch), loads issued after the barrier
// so its vmcnt(0) drain doesn't serialize them; consumed next stage phase.
// P via wave-local XOR-swizzled sP2 (8 b64 writes + 4 b128 reads).
// LDS: sK 16K + sVt 17K + sP2 16K = 49K -> 3 blocks/CU.
// ---------------------------------------------------------------------------
__global__ __launch_bounds__(256, 3)
void attn_kernel(const u16* __restrict__ qp, const u16* __restrict__ kp,
                 const u16* __restrict__ vp, int lds_,
                 const int* __restrict__ mask, u16* __restrict__ ctx,
                 const int* __restrict__ mflag) {
  __shared__ __align__(16) u16 sK[128 * 64];
  __shared__ __align__(16) u16 sVt[64 * 136];
  __shared__ __align__(16) unsigned sP2[4][1024];

  const bool nomask = (*mflag != 0);
  const long boff = (long)blockIdx.y * SEQ * (long)lds_;
  qp += boff; kp += boff; vp += boff;
  mask += (size_t)blockIdx.y * ((size_t)SEQ * SEQ);
  ctx += (size_t)blockIdx.y * ((size_t)SEQ * DM);

  const int id = (blockIdx.x & 7) * ((int)gridDim.x >> 3) + (blockIdx.x >> 3);
  const int q0 = (id & 31) << 6;
  const int h  = id >> 5;
  const int t = threadIdx.x, lane = t & 63, w = t >> 6;
  const int hoff = h << 6;
  const int lm = lane & 15, lg = lane >> 4;
  const int myq = q0 + (w << 4) + lm;        // this lane's softmax row
  const int aslot = 20 * lg;                  // shfl src: lane lg*16 + (lg*4+r)

  // staging geometry
  const int kq = (t & 31) << 2, dg = (t >> 5) << 3;
  const int vcol = kq ^ (((t >> 5) & 1) << 3);   // sVt write col (row-swizzled)
  unsigned* pw = &sP2[w][0];
  const int wswz = (lm & 7) << 2;
  const int pwb = lm << 6;
  const int vrs = ((lm >> 3) & 1) << 3;       // sVt read col swizzle

  // Q fragments: row myq, octets lg and 4+lg
  sx8 aq[2];
#pragma unroll
  for (int s = 0; s < 2; ++s)
    aq[s] = *(const sx8*)&qp[(size_t)myq * lds_ + hoff + (((s << 2) + lg) << 3)];

  fx4 o[4];
#pragma unroll
  for (int i = 0; i < 4; ++i) o[i] = (fx4){0.f, 0.f, 0.f, 0.f};
  float m_prev = -1e30f, lsum = 0.f;
  const float SCL = 0.18033688f;    // 0.125 * log2(e)
  const float RTHR = 44.36142f;     // 8 / SCL (defer-max bound, raw domain)

  // V prefetch (tile 0) in NAMED registers
  const u16* vbase = vp + (size_t)kq * lds_ + hoff + dg;
  uint4 va = *(const uint4*)(vbase);
  uint4 vb_ = *(const uint4*)(vbase + (size_t)lds_);
  uint4 vc = *(const uint4*)(vbase + 2 * (size_t)lds_);
  uint4 vd = *(const uint4*)(vbase + 3 * (size_t)lds_);

  for (int kt = 0; kt < 16; ++kt) {
    const int k0 = kt << 7;
    __syncthreads();                 // prev compute done; LDS reusable
    // K -> sK via global_load_lds (swizzled source, linear LDS)
#pragma unroll
    for (int it = 0; it < 4; ++it) {
      int ci = (it << 8) + t;
      int r = ci >> 3, cs = (ci & 7) ^ (r & 7);
      async16(&kp[(size_t)(k0 + r) * lds_ + hoff + (cs << 3)], &sK[ci << 3]);
    }
    // V regs -> sVt transposed (perm-pack, 8x b64 writes, swizzled col)
    {
      const unsigned A0[4] = {va.x, va.y, va.z, va.w};
      const unsigned B0[4] = {vb_.x, vb_.y, vb_.z, vb_.w};
      const unsigned C0[4] = {vc.x, vc.y, vc.z, vc.w};
      const unsigned D0[4] = {vd.x, vd.y, vd.z, vd.w};
#pragma unroll
      for (int j = 0; j < 8; ++j) {
        const unsigned sel = (j & 1) ? 0x07060302u : 0x05040100u;
        ux2 wv;
        wv[0] = __builtin_amdgcn_perm(B0[j >> 1], A0[j >> 1], sel);
        wv[1] = __builtin_amdgcn_perm(D0[j >> 1], C0[j >> 1], sel);
        *(ux2*)&sVt[(size_t)(dg + j) * 136 + vcol] = wv;
      }
    }
    __syncthreads();                 // drains asyncK + sVt writes

    // prefetch next V AFTER the barrier (not drained by it); hides under compute
    if (kt + 1 < 16) {
      const u16* vn = vbase + (size_t)(k0 + 128) * lds_;
      va = *(const uint4*)(vn);
      vb_ = *(const uint4*)(vn + (size_t)lds_);
      vc = *(const uint4*)(vn + 2 * (size_t)lds_);
      vd = *(const uint4*)(vn + 3 * (size_t)lds_);
    }

    // ---- QK^T swapped: lane holds S[q=lm][k=nt*16+lg*4+r] (raw scores) ----
    fx4 sc[8];
#pragma unroll
    for (int nt = 0; nt < 8; ++nt) sc[nt] = (fx4){0.f, 0.f, 0.f, 0.f};
    __builtin_amdgcn_s_setprio(1);
#pragma unroll
    for (int s = 0; s < 2; ++s) {
      const int g = (s << 2) + lg;
#pragma unroll
      for (int nt = 0; nt < 8; ++nt) {
        int rk = (nt << 4) + lm;
        sx8 bk = *(const sx8*)&sK[rk * 64 + ((g ^ (rk & 7)) << 3)];
        sc[nt] = __builtin_amdgcn_mfma_f32_16x16x32_bf16(bk, aq[s], sc[nt], 0, 0, 0);
      }
    }
    __builtin_amdgcn_s_setprio(0);

    if (!nomask) {
#pragma unroll
      for (int nt = 0; nt < 8; ++nt)
#pragma unroll
        for (int r = 0; r < 4; ++r) {
          const int col = k0 + (nt << 4) + (lg << 2) + r;
          if (mask[((size_t)myq << 11) + col] == 0) sc[nt][r] = -1e9f;
        }
    }

    float tm = sc[0][0];
#pragma unroll
    for (int nt = 0; nt < 8; ++nt)
#pragma unroll
      for (int r = 0; r < 4; ++r) tm = fmaxf(tm, sc[nt][r]);
    tm = fmaxf(tm, __shfl_xor(tm, 16));
    tm = fmaxf(tm, __shfl_xor(tm, 32));

    if (!__all(tm <= m_prev + RTHR)) {     // defer-max: rescale rarely
      const float mn = fmaxf(m_prev, tm);
      const float alpha = fexp2((m_prev - mn) * SCL);
      lsum *= alpha;
#pragma unroll
      for (int r = 0; r < 4; ++r) {
        float ar = __shfl(alpha, aslot + r);
#pragma unroll
        for (int ot = 0; ot < 4; ++ot) o[ot][r] *= ar;
      }
      m_prev = mn;
    }

    const float msc = m_prev * SCL;
    float rs = 0.f;
    float pvv[8][4];
#pragma unroll
    for (int nt = 0; nt < 8; ++nt)
#pragma unroll
      for (int r = 0; r < 4; ++r) {
        float e = fexp2(__builtin_fmaf(sc[nt][r], SCL, -msc));
        pvv[nt][r] = e;
        rs += e;
      }
    rs += __shfl_xor(rs, 16);
    rs += __shfl_xor(rs, 32);
    lsum += rs;

    // P -> bf16 pairs, wave-local swizzled LDS
    unsigned cpk[8][2];
#pragma unroll
    for (int nt = 0; nt < 8; ++nt) {
      asm("v_cvt_pk_bf16_f32 %0, %1, %2" : "=v"(cpk[nt][0]) : "v"(pvv[nt][0]), "v"(pvv[nt][1]));
      asm("v_cvt_pk_bf16_f32 %0, %1, %2" : "=v"(cpk[nt][1]) : "v"(pvv[nt][2]), "v"(pvv[nt][3]));
    }
#pragma unroll
    for (int nt = 0; nt < 8; ++nt)
      *(ux2*)&pw[pwb + (((nt << 3) + (lg << 1)) ^ wswz)] = (ux2){cpk[nt][0], cpk[nt][1]};

    // PV: A-frag = P[q=lm][k=ks*32+lg*8+e] from sP2; B = sVt
    __builtin_amdgcn_s_setprio(1);
#pragma unroll
    for (int ks = 0; ks < 4; ++ks) {
      sx8 ap = *(const sx8*)&pw[pwb + (((ks << 4) + (lg << 2)) ^ wswz)];
#pragma unroll
      for (int ot = 0; ot < 4; ++ot) {
        int d = (ot << 4) + lm;
        sx8 bv = *(const sx8*)&sVt[d * 136 + (((ks << 5) + (lg << 3)) ^ vrs)];
        o[ot] = __builtin_amdgcn_mfma_f32_16x16x32_bf16(ap, bv, o[ot], 0, 0, 0);
      }
    }
    __builtin_amdgcn_s_setprio(0);
  }

  float inv = (lsum > 0.f) ? 1.f / lsum : 0.f;
#pragma unroll
  for (int r = 0; r < 4; ++r) {
    float ir = __shfl(inv, aslot + r);
#pragma unroll
    for (int ot = 0; ot < 4; ++ot) {
      const int rowg = q0 + (w << 4) + (lg << 2) + r;
      const int col = hoff + (ot << 4) + lm;
      ctx[((size_t)rowg << 10) + col] = f2b(o[ot][r] * ir);
    }
  }
}

// ---------------------------------------------------------------------------
__global__ __launch_bounds__(256)
void ln_dual(const u16* __restrict__ a, const void* __restrict__ res, long roff,
             const void* __restrict__ g1, const void* __restrict__ b1,
             const void* __restrict__ gf, const void* __restrict__ bf,
             u16* __restrict__ xo, u16* __restrict__ xlo, const int* f_p) {
  __shared__ float red[8];
  const bool f = (*f_p != 0);
  const int row = blockIdx.x, t = threadIdx.x;
  const int lane = t & 63, w = t >> 6;
  const size_t base = (size_t)row << 10;
  const int c = t << 2;

  ushx4 a4 = *(const ushx4*)(a + base + c);
  float rv[4];
  ld4f(res, roff + (long)base + c, f, rv);
  float v[4], s = 0.f, ss = 0.f;
#pragma unroll
  for (int j = 0; j < 4; ++j) { v[j] = b2f(a4[j]) + rv[j]; s += v[j]; ss += v[j] * v[j]; }
#pragma unroll
  for (int off = 32; off > 0; off >>= 1) { s += __shfl_xor(s, off); ss += __shfl_xor(ss, off); }
  if (lane == 0) { red[w] = s; red[4 + w] = ss; }
  __syncthreads();
  s = red[0] + red[1] + red[2] + red[3];
  ss = red[4] + red[5] + red[6] + red[7];
  float mu = s * (1.f / 1024.f);
  float rstd = rsqrtf(fmaxf(ss * (1.f / 1024.f) - mu * mu, 0.f) + 1e-5f);

  float g4[4], b4[4];
  ld4f(g1, c, f, g4); ld4f(b1, c, f, b4);
  float x[4], s2 = 0.f, ss2 = 0.f;
  ushx4 xo4;
#pragma unroll
  for (int j = 0; j < 4; ++j) {
    x[j] = (v[j] - mu) * rstd * g4[j] + b4[j];
    xo4[j] = f2b(x[j]);
    s2 += x[j]; ss2 += x[j] * x[j];
  }
  *(ushx4*)(xo + base + c) = xo4;
#pragma unroll
  for (int off = 32; off > 0; off >>= 1) { s2 += __shfl_xor(s2, off); ss2 += __shfl_xor(ss2, off); }
  __syncthreads();
  if (lane == 0) { red[w] = s2; red[4 + w] = ss2; }
  __syncthreads();
  s2 = red[0] + red[1] + red[2] + red[3];
  ss2 = red[4] + red[5] + red[6] + red[7];
  float mu2 = s2 * (1.f / 1024.f);
  float rstd2 = rsqrtf(fmaxf(ss2 * (1.f / 1024.f) - mu2 * mu2, 0.f) + 1e-5f);

  ld4f(gf, c, f, g4); ld4f(bf, c, f, b4);
  ushx4 xl4;
#pragma unroll
  for (int j = 0; j < 4; ++j)
    xl4[j] = f2b((x[j] - mu2) * rstd2 * g4[j] + b4[j]);
  *(ushx4*)(xlo + base + c) = xl4;
}

// ---------------------------------------------------------------------------
__global__ __launch_bounds__(256)
void ln_final(const u16* __restrict__ a, const u16* __restrict__ resx,
              const void* __restrict__ g, const void* __restrict__ bb,
              void* __restrict__ out, long ooff, const int* f_p) {
  __shared__ float red[8];
  const bool f = (*f_p != 0);
  const int row = blockIdx.x, t = threadIdx.x;
  const int lane = t & 63, w = t >> 6;
  const size_t base = (size_t)row << 10;
  const int c = t << 2;

  ushx4 a4 = *(const ushx4*)(a + base + c);
  ushx4 r4 = *(const ushx4*)(resx + base + c);
  float v[4], s = 0.f, ss = 0.f;
#pragma unroll
  for (int j = 0; j < 4; ++j) { v[j] = b2f(a4[j]) + b2f(r4[j]); s += v[j]; ss += v[j] * v[j]; }
#pragma unroll
  for (int off = 32; off > 0; off >>= 1) { s += __shfl_xor(s, off); ss += __shfl_xor(ss, off); }
  if (lane == 0) { red[w] = s; red[4 + w] = ss; }
  __syncthreads();
  s = red[0] + red[1] + red[2] + red[3];
  ss = red[4] + red[5] + red[6] + red[7];
  float mu = s * (1.f / 1024.f);
  float rstd = rsqrtf(fmaxf(ss * (1.f / 1024.f) - mu * mu, 0.f) + 1e-5f);

  float g4[4], b4[4];
  ld4f(g, c, f, g4); ld4f(bb, c, f, b4);
  if (f) {
    fx4 o4;
#pragma unroll
    for (int j = 0; j < 4; ++j) o4[j] = (v[j] - mu) * rstd * g4[j] + b4[j];
    *(fx4*)((float*)out + ooff + base + c) = o4;
  } else {
    ushx4 o4;
#pragma unroll
    for (int j = 0; j < 4; ++j) o4[j] = f2b((v[j] - mu) * rstd * g4[j] + b4[j]);
    *(ushx4*)((u16*)out + ooff + base + c) = o4;
  }
}

// ---------------------------------------------------------------------------
extern "C" void kernel_launch(void* const* d_in, const int* in_sizes, int n_in,
                              void* d_out, int out_size, void* d_ws, size_t ws_size,
                              hipStream_t stream) {
  (void)in_sizes; (void)n_in; (void)out_size;
  const void* query = d_in[0];
  const void* keyi  = d_in[1];
  const void* value = d_in[2];
  const int*  mask  = (const int*)d_in[3];
  const void* Wq = d_in[4];
  const void* Wk = d_in[5];
  const void* Wv = d_in[6];
  const void* Wo = d_in[7];
  const void* bo = d_in[8];
  const void* g1 = d_in[9];
  const void* b1 = d_in[10];
  const void* g2 = d_in[11];
  const void* b2 = d_in[12];
  const void* gff = d_in[13];
  const void* bff = d_in[14];
  const void* W1 = d_in[15];
  const void* bf1 = d_in[16];
  const void* W2 = d_in[17];
  const void* bf2 = d_in[18];

  char* p = (char*)d_ws;
  int* flags = (int*)p;
  const int* F = flags;
  const int* Z = flags + 1;
  const int* M = flags + 2;
  dim3 blk(256);

  // footprint(CH) = 4096 + 24MiB (packed weights) + 7*CH*2048 bytes
  const size_t FIXED = 4096 + ((size_t)24 << 20);
  const size_t needC = FIXED + (size_t)8192 * 14336;   // ~142.6 MB
  const size_t needA = FIXED + (size_t)4096 * 14336;   // ~80.0 MB
  const size_t needB = FIXED + (size_t)2048 * 14336;   // ~52.0 MB

  if (ws_size >= needB) {
    // ------------------------- NEW PATH -------------------------
    const int CH = (ws_size >= needC) ? 8192 : (ws_size >= needA) ? 4096 : 2048;
    const int nch = 8192 / CH;

    u16* Wqkv  = (u16*)(p + 4096);                       // [3*1024,1024]
    u16* Wo_bf = Wqkv + (size_t)3 * DM * DM;             // [1024,1024]
    u16* W1T   = Wo_bf + (size_t)DM * DM;                // [4096,1024]
    u16* W2T   = W1T + (size_t)DFF * DM;                 // [1024,4096]
    u16* D0    = W2T + (size_t)DM * DFF;                 // in_bf / h
    u16* D1    = D0 + (size_t)3 * CH * DM;               // qkv / ao,x,xln
    u16* D2    = D1 + (size_t)3 * CH * DM;               // ctx / ff
    u16* qb = D0;
    u16* qkv = D1;
    u16* ao = D1, *x = D1 + (size_t)CH * DM, *xln = D1 + (size_t)2 * CH * DM;
    u16* h = D0;                                         // CH*4096 elems
    u16* ctx = D2, *ff = D2;

    detect_kernel<<<1, 64, 0, stream>>>(query, flags);
    mask_scan<<<dim3(8192), blk, 0, stream>>>(mask, flags);
    pack_w<<<dim3(2048), blk, 0, stream>>>(Wq, Wk, Wv, Wo, Wqkv, Wo_bf, F);
    transpose_any<<<dim3(DFF / 64, DM / 64), blk, 0, stream>>>(W1, W1T, DM, DFF, F);
    transpose_any<<<dim3(DM / 64, DFF / 64), blk, 0, stream>>>(W2, W2T, DFF, DM, F);

    for (int c = 0; c < nch; ++c) {
      const long off = (long)c * CH * DM;
      const long n = (long)CH * DM;
      conv_bf3<<<dim3((int)(n >> 11), 3), blk, 0, stream>>>(query, keyi, value, off, qb, n, F);

      // q/k/v projections co-dispatched: z in {0,1,2}
      gemm_bb<false, false, false><<<dim3((CH / 128) * 8, 3), blk, 0, stream>>>(
          qb, (long)CH * DM, Wqkv, (long)DM * DM, nullptr,
          qkv, 1024L, CH, DM, DM, 3072, Z);

      const int bpc = CH / SEQ, b0 = c * bpc;
      attn_kernel<<<dim3(512, bpc), blk, 0, stream>>>(
          qkv, qkv + 1024, qkv + 2048, 3072,
          mask + (size_t)b0 * SEQ * SEQ, ctx, M);

      gemm_bb<false, true, true><<<dim3((CH / 128) * 8, 1), blk, 0, stream>>>(
          ctx, 0, Wo_bf, 0, bo, ao, 0, CH, DM, DM, DM, F);

      ln_dual<<<dim3(CH), blk, 0, stream>>>(ao, query, off, g1, b1, gff, bff, x, xln, F);

      gemm_bb<true, true, false><<<dim3((CH / 128) * 32, 1), blk, 0, stream>>>(
          xln, 0, W1T, 0, bf1, h, 0, CH, DFF, DM, DFF, F);
      gemm_bb<false, true, true><<<dim3((CH / 128) * 8, 1), blk, 0, stream>>>(
          h, 0, W2T, 0, bf2, ff, 0, CH, DM, DFF, DM, F);

      ln_final<<<dim3(CH), blk, 0, stream>>>(ff, x, g2, b2, d_out, off, F);
    }
  } else {
    // ------------------------- LEGACY PATH (round-3 proven) -------------------------
    const int CH = 2048, FH = 1024;
    const int nch = 8192 / CH;
    const size_t h0 = 4096;
    u16* W1T = (u16*)(p + h0);
    u16* W2T = W1T + (size_t)DFF * DM;
    u16* hb  = (u16*)(p + h0 + ((size_t)16 << 20));
    const size_t HB = (size_t)FH * DFF * 2;
    u16* r0 = (u16*)(p + h0 + ((size_t)16 << 20) + HB);
    const size_t CE = (size_t)CH * DM;
    u16* qp = r0;
    u16* kp = qp + CE;
    u16* vp = kp + CE;
    u16* ctxb = vp + CE;
    u16* x = qp; u16* xln = kp; u16* ao = vp; u16* ff = ctxb;

    detect_kernel<<<1, 64, 0, stream>>>(query, flags);
    mask_scan<<<dim3(8192), blk, 0, stream>>>(mask, flags);
    transpose_any<<<dim3(DFF / 64, DM / 64), blk, 0, stream>>>(W1, W1T, DM, DFF, F);
    transpose_any<<<dim3(DM / 64, DFF / 64), blk, 0, stream>>>(W2, W2T, DFF, DM, F);

    for (int c = 0; c < nch; ++c) {
      const long off = (long)c * CH * DM;
      dim3 gq((CH / 128) * (DM / 128));

      gemm_nt<false, false><<<gq, blk, 0, stream>>>(query, off, Wq, Wq, qp, CH, DM, DM, F, F, Z);
      gemm_nt<false, false><<<gq, blk, 0, stream>>>(keyi,  off, Wk, Wk, kp, CH, DM, DM, F, F, Z);
      gemm_nt<false, false><<<gq, blk, 0, stream>>>(value, off, Wv, Wv, vp, CH, DM, DM, F, F, Z);

      const int bpc = CH / SEQ, b0 = c * bpc;
      for (int bl = 0; bl < bpc; ++bl) {
        const size_t lo = (size_t)bl * SEQ * DM;
        attn_kernel<<<dim3(512, 1), blk, 0, stream>>>(
            qp + lo, kp + lo, vp + lo, 1024,
            mask + (size_t)(b0 + bl) * SEQ * SEQ, ctxb + lo, M);
      }

      gemm_nt<false, true><<<gq, blk, 0, stream>>>(ctxb, 0, Wo, bo, ao, CH, DM, DM, Z, F, F);

      ln_dual<<<dim3(CH), blk, 0, stream>>>(ao, query, off, g1, b1, gff, bff, x, xln, F);

      for (int qs = 0; qs < CH / FH; ++qs) {
        const long so = (long)qs * FH * DM;
        gemm_nt<true, true><<<dim3((FH / 128) * (DFF / 128)), blk, 0, stream>>>(
            xln + so, 0, W1T, bf1, hb, FH, DFF, DM, Z, Z, F);
        gemm_nt<false, true><<<dim3((FH / 128) * (DM / 128)), blk, 0, stream>>>(
            hb, 0, W2T, bf2, ff + so, FH, DM, DFF, Z, Z, F);
      }

      ln_final<<<dim3(CH), blk, 0, stream>>>(ff, x, g2, b2, d_out, off, F);
    }
  }
}

// Round 5
// 639.944 us; speedup vs baseline: 1.4722x; 1.1121x over previous
//
#include <hip/hip_runtime.h>

// ---------------------------------------------------------------------------
// SublayerConnection: MHA + residual/LN + FF + residual/LN
// B=4 S=2048 D=1024 H=16 Dk=64 Dff=4096.
// Round 9: (1) attn sVt -> GEMM-style [128][64] XOR-granule layout (the
// measured-0-conflict pattern); kills the 14.7M-conflict b128 PV reads.
// (2) sP aliases sK (P written after QK consumed K; extra raw s_barrier),
// LDS 49->32KB -> 4 blocks/CU. (3) gemm_bb DBUF: 2 buffers (64KB -> 2
// blocks/CU), vmcnt(8) BEFORE the pre-compute barrier (cross-wave sound),
// raw barriers so prefetch spans compute.
// ---------------------------------------------------------------------------

#define DM   1024
#define DFF  4096
#define SEQ  2048

typedef unsigned short u16;
typedef short          sx8  __attribute__((ext_vector_type(8)));
typedef unsigned short ushx8 __attribute__((ext_vector_type(8)));
typedef unsigned short ushx4 __attribute__((ext_vector_type(4)));
typedef float          fx4  __attribute__((ext_vector_type(4)));
typedef unsigned int   ux2  __attribute__((ext_vector_type(2)));

__device__ __forceinline__ void async16(const void* g, void* l) {
  __builtin_amdgcn_global_load_lds((__attribute__((address_space(1))) void*)g,
                                   (__attribute__((address_space(3))) void*)l,
                                   16, 0, 0);
}
__device__ __forceinline__ float b2f(u16 u) {
  union { unsigned int i; float f; } v; v.i = ((unsigned int)u) << 16; return v.f;
}
__device__ __forceinline__ u16 f2b(float f) {
  union { float f; unsigned int i; } v; v.f = f;
  unsigned int r = v.i + 0x7fffu + ((v.i >> 16) & 1u);
  return (u16)(r >> 16);
}
__device__ __forceinline__ float fexp2(float x) {
#if __has_builtin(__builtin_amdgcn_exp2f)
  return __builtin_amdgcn_exp2f(x);
#else
  return exp2f(x);
#endif
}
__device__ __forceinline__ ushx8 ld8(const void* p, long idx, bool f32) {
  if (f32) {
    const float* s = (const float*)p + idx;
    fx4 a = *(const fx4*)s, b = *(const fx4*)(s + 4);
    ushx8 r;
    r[0] = f2b(a[0]); r[1] = f2b(a[1]); r[2] = f2b(a[2]); r[3] = f2b(a[3]);
    r[4] = f2b(b[0]); r[5] = f2b(b[1]); r[6] = f2b(b[2]); r[7] = f2b(b[3]);
    return r;
  }
  return *(const ushx8*)((const u16*)p + idx);
}
__device__ __forceinline__ void ld4f(const void* p, long idx, bool f32, float* o) {
  if (f32) {
    fx4 a = *(const fx4*)((const float*)p + idx);
    o[0] = a[0]; o[1] = a[1]; o[2] = a[2]; o[3] = a[3];
  } else {
    ushx4 a = *(const ushx4*)((const u16*)p + idx);
    o[0] = b2f(a[0]); o[1] = b2f(a[1]); o[2] = b2f(a[2]); o[3] = b2f(a[3]);
  }
}

// ---------------------------------------------------------------------------
__global__ void detect_kernel(const void* q, int* flags) {
  int lane = threadIdx.x;
  u16 v = ((const u16*)q)[lane << 1];
  int e = (v >> 7) & 0xff;
  int pl = (e >= 0x60 && e <= 0x8c) ? 1 : 0;
  unsigned long long m = __ballot(pl);
  if (lane == 0) { flags[0] = (__popcll(m) >= 40) ? 0 : 1; flags[1] = 0; flags[2] = 1; }
}

// Scan mask for any zero; flags[2] stays 1 iff every element nonzero.
__global__ __launch_bounds__(256)
void mask_scan(const int* __restrict__ m, int* flags) {
  long i = (((long)blockIdx.x << 8) + threadIdx.x) << 3;
  const int4 a = *(const int4*)(m + i);
  const int4 b = *(const int4*)(m + i + 4);
  bool ok = a.x && a.y && a.z && a.w && b.x && b.y && b.z && b.w;
  if (!__all(ok)) { if ((threadIdx.x & 63) == 0) flags[2] = 0; }
}

// Pack Wq/Wk/Wv -> Wqkv [3*1024,1024] bf16 and Wo -> bf16.
__global__ __launch_bounds__(256)
void pack_w(const void* Wq, const void* Wk, const void* Wv, const void* Wo,
            u16* Wqkv, u16* Wo_bf, const int* f_p) {
  const bool f = (*f_p != 0);
  long i = (((long)blockIdx.x << 8) + threadIdx.x) << 3;
  const long QKVN = (long)3 * DM * DM;
  if (i < QKVN) {
    int row = (int)(i >> 10);
    const void* src = (row < DM) ? Wq : (row < 2 * DM ? Wk : Wv);
    long s = ((long)(row & (DM - 1)) << 10) + (i & 1023);
    *(ushx8*)(Wqkv + i) = ld8(src, s, f);
  } else {
    long j = i - QKVN;
    *(ushx8*)(Wo_bf + j) = ld8(Wo, j, f);
  }
}

// Convert q/k/v chunk to bf16; grid.y selects source, dst stride n.
__global__ __launch_bounds__(256)
void conv_bf3(const void* q, const void* k, const void* v, long off,
              u16* dst, long n, const int* f_p) {
  const bool f = (*f_p != 0);
  const void* src = (blockIdx.y == 0) ? q : (blockIdx.y == 1 ? k : v);
  long i = (((long)blockIdx.x << 8) + threadIdx.x) << 3;
  if (i < n) *(ushx8*)(dst + (long)blockIdx.y * n + i) = ld8(src, off + i, f);
}

// ---------------------------------------------------------------------------
// Pure-bf16 NT GEMM with global_load_lds(16B) staging. C=A@B^T (+bias)(+relu).
// grid.y = z selects (A,B,C) via element strides az/bz/cz. C row stride ldc.
// DBUF: 2 LDS buffers (64KB -> 2 blocks/CU), prefetch-next then vmcnt(8)
// BEFORE the pre-compute raw barrier: every wave certifies its own tile-n
// loads landed, so post-barrier all waves' are; prefetch spans the compute.
// Post-compute barrier protects the buffer restaged next iteration.
// All grids %8==0 -> bijective XCD swizzle.
// ---------------------------------------------------------------------------
template<bool RELU, bool BIAS, bool DBUF>
__global__ __launch_bounds__(256)
void gemm_bb(const u16* __restrict__ A, long az, const u16* __restrict__ B, long bz,
             const void* __restrict__ bias, u16* __restrict__ C, long cz,
             int M, int N, int K, int ldc, const int* biasf_p) {
  __shared__ __align__(16) u16 sA[(DBUF ? 2 : 1) * 128 * 64];
  __shared__ __align__(16) u16 sB[(DBUF ? 2 : 1) * 128 * 64];
  const int z = blockIdx.y;
  A += (long)z * az; B += (long)z * bz; C += (long)z * cz;
  const bool biasf = BIAS && (*biasf_p != 0);
  const int t = threadIdx.x;
  const int lane = t & 63, w = t >> 6;
  const int lm = lane & 15, lg = lane >> 4;
  const int ntil = N >> 7;
  // XCD-aware bijective swizzle (gridDim.x % 8 == 0 for all dispatches)
  const int bx = (blockIdx.x & 7) * ((int)gridDim.x >> 3) + (blockIdx.x >> 3);
  const int m0 = (bx / ntil) << 7;
  const int n0 = (bx % ntil) << 7;
  const int wm = (w & 1) << 6, wn = (w >> 1) << 6;

  fx4 acc[4][4];
#pragma unroll
  for (int i = 0; i < 4; ++i)
#pragma unroll
    for (int j = 0; j < 4; ++j) acc[i][j] = (fx4){0.f, 0.f, 0.f, 0.f};

  auto stage = [&](int so, int kt) {
#pragma unroll
    for (int it = 0; it < 4; ++it) {
      int ci = (it << 8) + t;
      int r = ci >> 3, cs = (ci & 7) ^ (r & 7);
      async16(&A[(size_t)(m0 + r) * K + kt + (cs << 3)], &sA[so + (ci << 3)]);
    }
#pragma unroll
    for (int it = 0; it < 4; ++it) {
      int ci = (it << 8) + t;
      int r = ci >> 3, cs = (ci & 7) ^ (r & 7);
      async16(&B[(size_t)(n0 + r) * K + kt + (cs << 3)], &sB[so + (ci << 3)]);
    }
  };

  auto compute = [&](int so) {
#pragma unroll
    for (int s = 0; s < 2; ++s) {
      const int g = (s << 2) + lg;
      sx8 afr[4], bfr[4];
#pragma unroll
      for (int i = 0; i < 4; ++i) {
        int ra = wm + (i << 4) + lm;
        afr[i] = *(const sx8*)&sA[so + ra * 64 + ((g ^ (ra & 7)) << 3)];
        int rb = wn + (i << 4) + lm;
        bfr[i] = *(const sx8*)&sB[so + rb * 64 + ((g ^ (rb & 7)) << 3)];
      }
      __builtin_amdgcn_s_setprio(1);
#pragma unroll
      for (int i = 0; i < 4; ++i)
#pragma unroll
        for (int j = 0; j < 4; ++j)
          acc[i][j] = __builtin_amdgcn_mfma_f32_16x16x32_bf16(afr[i], bfr[j], acc[i][j], 0, 0, 0);
      __builtin_amdgcn_s_setprio(0);
    }
  };

  if (DBUF) {
    const int NT = K >> 6;
    stage(0, 0);
    for (int n = 0; n < NT; ++n) {
      if (n + 1 < NT) {
        stage(((n + 1) & 1) << 13, (n + 1) << 6);   // prefetch next tile
        asm volatile("s_waitcnt vmcnt(8)" ::: "memory");  // own tile-n landed
      } else {
        asm volatile("s_waitcnt vmcnt(0)" ::: "memory");
      }
      __builtin_amdgcn_s_barrier();                 // all waves' tile-n landed
      __builtin_amdgcn_sched_barrier(0);
      compute((n & 1) << 13);
      if (n + 1 < NT) __builtin_amdgcn_s_barrier(); // buf free before restage
    }
  } else {
    for (int kt = 0; kt < K; kt += 64) {
      __syncthreads();
      stage(0, kt);
      __syncthreads();
      compute(0);
    }
  }

#pragma unroll
  for (int j = 0; j < 4; ++j) {
    const int col = n0 + wn + (j << 4) + lm;
    float bv = 0.f;
    if (BIAS) bv = biasf ? ((const float*)bias)[col] : b2f(((const u16*)bias)[col]);
#pragma unroll
    for (int i = 0; i < 4; ++i) {
      const int row0 = m0 + wm + (i << 4) + (lg << 2);
#pragma unroll
      for (int r = 0; r < 4; ++r) {
        float v = acc[i][j][r] + bv;
        if (RELU) v = fmaxf(v, 0.f);
        C[(size_t)(row0 + r) * ldc + col] = f2b(v);
      }
    }
  }
}

// ---------------------------------------------------------------------------
// Flag-dtype NT GEMM (legacy path, proven in round 3).
// ---------------------------------------------------------------------------
template<bool RELU, bool BIAS>
__global__ __launch_bounds__(256)
void gemm_nt(const void* __restrict__ A, long aoff, const void* __restrict__ Bm,
             const void* __restrict__ bias, u16* __restrict__ C,
             int M, int N, int K,
             const int* af_p, const int* bf_p, const int* biasf_p) {
  __shared__ __align__(16) u16 sA[128 * 64];
  __shared__ __align__(16) u16 sB[128 * 64];
  const bool af = (*af_p != 0), bfl = (*bf_p != 0), biasf = (*biasf_p != 0);
  const int t = threadIdx.x;
  const int lane = t & 63, w = t >> 6;
  const int lm = lane & 15, lg = lane >> 4;
  const int ntil = N >> 7;
  const int m0 = (blockIdx.x / ntil) << 7;
  const int n0 = (blockIdx.x % ntil) << 7;
  const int wm = (w & 1) << 6, wn = (w >> 1) << 6;

  fx4 acc[4][4];
#pragma unroll
  for (int i = 0; i < 4; ++i)
#pragma unroll
    for (int j = 0; j < 4; ++j) acc[i][j] = (fx4){0.f, 0.f, 0.f, 0.f};

  for (int kt = 0; kt < K; kt += 64) {
    __syncthreads();
#pragma unroll
    for (int it = 0; it < 4; ++it) {
      int ci = (it << 8) + t;
      int r = ci >> 3, cs = (ci & 7) ^ (r & 7);
      ushx8 va = ld8(A, aoff + (long)(m0 + r) * K + kt + (cs << 3), af);
      *(ushx8*)&sA[ci << 3] = va;
      ushx8 vb = ld8(Bm, (long)(n0 + r) * K + kt + (cs << 3), bfl);
      *(ushx8*)&sB[ci << 3] = vb;
    }
    __syncthreads();
#pragma unroll
    for (int s = 0; s < 2; ++s) {
      const int g = (s << 2) + lg;
      sx8 afr[4], bfr[4];
#pragma unroll
      for (int i = 0; i < 4; ++i) {
        int ra = wm + (i << 4) + lm;
        afr[i] = *(const sx8*)&sA[ra * 64 + ((g ^ (ra & 7)) << 3)];
        int rb = wn + (i << 4) + lm;
        bfr[i] = *(const sx8*)&sB[rb * 64 + ((g ^ (rb & 7)) << 3)];
      }
#pragma unroll
      for (int i = 0; i < 4; ++i)
#pragma unroll
        for (int j = 0; j < 4; ++j)
          acc[i][j] = __builtin_amdgcn_mfma_f32_16x16x32_bf16(afr[i], bfr[j], acc[i][j], 0, 0, 0);
    }
  }

#pragma unroll
  for (int j = 0; j < 4; ++j) {
    const int col = n0 + wn + (j << 4) + lm;
    float bv = 0.f;
    if (BIAS) bv = biasf ? ((const float*)bias)[col] : b2f(((const u16*)bias)[col]);
#pragma unroll
    for (int i = 0; i < 4; ++i) {
      const int row0 = m0 + wm + (i << 4) + (lg << 2);
#pragma unroll
      for (int r = 0; r < 4; ++r) {
        float v = acc[i][j][r] + bv;
        if (RELU) v = fmaxf(v, 0.f);
        C[(size_t)(row0 + r) * N + col] = f2b(v);
      }
    }
  }
}

// ---------------------------------------------------------------------------
__global__ __launch_bounds__(256)
void transpose_any(const void* __restrict__ in, u16* __restrict__ out,
                   int R, int C, const int* f_p) {
  __shared__ u16 tile[64][68];
  const bool f = (*f_p != 0);
  const int r0 = blockIdx.y << 6, c0 = blockIdx.x << 6;
  const int t = threadIdx.x;
#pragma unroll
  for (int it = 0; it < 4; ++it) {
    int j = (it << 8) + t;
    int rr = j >> 4, cc4 = (j & 15) << 2;
    float v[4];
    ld4f(in, (long)(r0 + rr) * C + c0 + cc4, f, v);
#pragma unroll
    for (int q = 0; q < 4; ++q) tile[rr][cc4 + q] = f2b(v[q]);
  }
  __syncthreads();
#pragma unroll
  for (int it = 0; it < 4; ++it) {
    int j = (it << 8) + t;
    int cc = j >> 4, rr4 = (j & 15) << 2;
    ushx4 v;
    v[0] = tile[rr4 + 0][cc]; v[1] = tile[rr4 + 1][cc];
    v[2] = tile[rr4 + 2][cc]; v[3] = tile[rr4 + 3][cc];
    *(ushx4*)&out[(size_t)(c0 + cc) * R + r0 + rr4] = v;
  }
}

// ---------------------------------------------------------------------------
// Flash attention, swapped-QK^T. grid.x = 512 (XCD-swizzled); grid.y = batch.
// Per wave 16 q rows; lane (lm,lg) owns softmax row q=lm for k=nt*16+lg*4+r.
// K via global_load_lds. V prefetched in 4 NAMED uint4 regs. sVt stored in
// GEMM-style [128][64] XOR-granule layout (row = (k>>6)*64+d, granule
// ((k>>3)&7)^(d&7)) -> PV b128 reads bank-identical to gemm (0-conflict).
// P LDS aliases sK (safe: written after QK^T consumed K; raw s_barrier
// in between). LDS = 32KB -> 4 blocks/CU.
// ---------------------------------------------------------------------------
__global__ __launch_bounds__(256, 4)
void attn_kernel(const u16* __restrict__ qp, const u16* __restrict__ kp,
                 const u16* __restrict__ vp, int lds_,
                 const int* __restrict__ mask, u16* __restrict__ ctx,
                 const int* __restrict__ mflag) {
  __shared__ __align__(16) u16 smem[16384];   // 32KB: sK(16K)|sVt(16K); sP aliases sK
  u16* const sK  = smem;
  u16* const sVt = smem + 8192;
  unsigned* const sPal = (unsigned*)smem;

  const bool nomask = (*mflag != 0);
  const long boff = (long)blockIdx.y * SEQ * (long)lds_;
  qp += boff; kp += boff; vp += boff;
  mask += (size_t)blockIdx.y * ((size_t)SEQ * SEQ);
  ctx += (size_t)blockIdx.y * ((size_t)SEQ * DM);

  const int id = (blockIdx.x & 7) * ((int)gridDim.x >> 3) + (blockIdx.x >> 3);
  const int q0 = (id & 31) << 6;
  const int h  = id >> 5;
  const int t = threadIdx.x, lane = t & 63, w = t >> 6;
  const int hoff = h << 6;
  const int lm = lane & 15, lg = lane >> 4;
  const int myq = q0 + (w << 4) + lm;        // this lane's softmax row
  const int aslot = 20 * lg;                  // shfl src: lane lg*16 + (lg*4+r)

  // staging geometry
  const int kq = (t & 31) << 2, dg = (t >> 5) << 3;
  const int kg7 = (kq >> 3) & 7;              // thread's k-quad granule
  const int k7o = kq & 7;                     // offset within granule (0 or 4)
  const int vbrow = ((kq >> 6) << 6) + dg;    // sVt base row for writes
  unsigned* pw = sPal + (w << 10);
  const int wswz = (lm & 7) << 2;
  const int pwb = lm << 6;

  // Q fragments: row myq, octets lg and 4+lg
  sx8 aq[2];
#pragma unroll
  for (int s = 0; s < 2; ++s)
    aq[s] = *(const sx8*)&qp[(size_t)myq * lds_ + hoff + (((s << 2) + lg) << 3)];

  fx4 o[4];
#pragma unroll
  for (int i = 0; i < 4; ++i) o[i] = (fx4){0.f, 0.f, 0.f, 0.f};
  float m_prev = -1e30f, lsum = 0.f;
  const float SCL = 0.18033688f;    // 0.125 * log2(e)
  const float RTHR = 44.36142f;     // 8 / SCL (defer-max bound, raw domain)

  // V prefetch (tile 0) in NAMED registers
  const u16* vbase = vp + (size_t)kq * lds_ + hoff + dg;
  uint4 va = *(const uint4*)(vbase);
  uint4 vb_ = *(const uint4*)(vbase + (size_t)lds_);
  uint4 vc = *(const uint4*)(vbase + 2 * (size_t)lds_);
  uint4 vd = *(const uint4*)(vbase + 3 * (size_t)lds_);

  for (int kt = 0; kt < 16; ++kt) {
    const int k0 = kt << 7;
    __syncthreads();                 // prev compute done; LDS reusable
    // K -> sK via global_load_lds (swizzled source, linear LDS)
#pragma unroll
    for (int it = 0; it < 4; ++it) {
      int ci = (it << 8) + t;
      int r = ci >> 3, cs = (ci & 7) ^ (r & 7);
      async16(&kp[(size_t)(k0 + r) * lds_ + hoff + (cs << 3)], &sK[ci << 3]);
    }
    // V regs -> sVt (perm-pack to V^T[d][k-quad], GEMM-style XOR layout)
    {
      const unsigned A0[4] = {va.x, va.y, va.z, va.w};
      const unsigned B0[4] = {vb_.x, vb_.y, vb_.z, vb_.w};
      const unsigned C0[4] = {vc.x, vc.y, vc.z, vc.w};
      const unsigned D0[4] = {vd.x, vd.y, vd.z, vd.w};
#pragma unroll
      for (int j = 0; j < 8; ++j) {
        const unsigned sel = (j & 1) ? 0x07060302u : 0x05040100u;
        ux2 wv;
        wv[0] = __builtin_amdgcn_perm(B0[j >> 1], A0[j >> 1], sel);
        wv[1] = __builtin_amdgcn_perm(D0[j >> 1], C0[j >> 1], sel);
        *(ux2*)&sVt[(vbrow + j) * 64 + ((kg7 ^ j) << 3) + k7o] = wv;
      }
    }
    __syncthreads();                 // drains asyncK + sVt writes

    // prefetch next V AFTER the barrier (not drained by it); hides under compute
    if (kt + 1 < 16) {
      const u16* vn = vbase + (size_t)(k0 + 128) * lds_;
      va = *(const uint4*)(vn);
      vb_ = *(const uint4*)(vn + (size_t)lds_);
      vc = *(const uint4*)(vn + 2 * (size_t)lds_);
      vd = *(const uint4*)(vn + 3 * (size_t)lds_);
    }

    // ---- QK^T swapped: lane holds S[q=lm][k=nt*16+lg*4+r] (raw scores) ----
    fx4 sc[8];
#pragma unroll
    for (int nt = 0; nt < 8; ++nt) sc[nt] = (fx4){0.f, 0.f, 0.f, 0.f};
    __builtin_amdgcn_s_setprio(1);
#pragma unroll
    for (int s = 0; s < 2; ++s) {
      const int g = (s << 2) + lg;
#pragma unroll
      for (int nt = 0; nt < 8; ++nt) {
        int rk = (nt << 4) + lm;
        sx8 bk = *(const sx8*)&sK[rk * 64 + ((g ^ (rk & 7)) << 3)];
        sc[nt] = __builtin_amdgcn_mfma_f32_16x16x32_bf16(bk, aq[s], sc[nt], 0, 0, 0);
      }
    }
    __builtin_amdgcn_s_setprio(0);

    if (!nomask) {
#pragma unroll
      for (int nt = 0; nt < 8; ++nt)
#pragma unroll
        for (int r = 0; r < 4; ++r) {
          const int col = k0 + (nt << 4) + (lg << 2) + r;
          if (mask[((size_t)myq << 11) + col] == 0) sc[nt][r] = -1e9f;
        }
    }

    float tm = sc[0][0];
#pragma unroll
    for (int nt = 0; nt < 8; ++nt)
#pragma unroll
      for (int r = 0; r < 4; ++r) tm = fmaxf(tm, sc[nt][r]);
    tm = fmaxf(tm, __shfl_xor(tm, 16));
    tm = fmaxf(tm, __shfl_xor(tm, 32));

    if (!__all(tm <= m_prev + RTHR)) {     // defer-max: rescale rarely
      const float mn = fmaxf(m_prev, tm);
      const float alpha = fexp2((m_prev - mn) * SCL);
      lsum *= alpha;
#pragma unroll
      for (int r = 0; r < 4; ++r) {
        float ar = __shfl(alpha, aslot + r);
#pragma unroll
        for (int ot = 0; ot < 4; ++ot) o[ot][r] *= ar;
      }
      m_prev = mn;
    }

    const float msc = m_prev * SCL;
    float rs = 0.f;
    float pvv[8][4];
#pragma unroll
    for (int nt = 0; nt < 8; ++nt)
#pragma unroll
      for (int r = 0; r < 4; ++r) {
        float e = fexp2(__builtin_fmaf(sc[nt][r], SCL, -msc));
        pvv[nt][r] = e;
        rs += e;
      }
    rs += __shfl_xor(rs, 16);
    rs += __shfl_xor(rs, 32);
    lsum += rs;

    // P -> bf16 pairs
    unsigned cpk[8][2];
#pragma unroll
    for (int nt = 0; nt < 8; ++nt) {
      asm("v_cvt_pk_bf16_f32 %0, %1, %2" : "=v"(cpk[nt][0]) : "v"(pvv[nt][0]), "v"(pvv[nt][1]));
      asm("v_cvt_pk_bf16_f32 %0, %1, %2" : "=v"(cpk[nt][1]) : "v"(pvv[nt][2]), "v"(pvv[nt][3]));
    }

    // all waves' QK^T sK reads are retired (consumed by MFMA) -> safe to
    // overwrite the aliased region. Raw barrier: no vmcnt drain, V-prefetch
    // stays in flight.
    __builtin_amdgcn_sched_barrier(0);
    __builtin_amdgcn_s_barrier();
    __builtin_amdgcn_sched_barrier(0);

    // P writes, wave-local swizzled (aliased onto sK region)
#pragma unroll
    for (int nt = 0; nt < 8; ++nt)
      *(ux2*)&pw[pwb + (((nt << 3) + (lg << 1)) ^ wswz)] = (ux2){cpk[nt][0], cpk[nt][1]};

    // PV: A-frag = P[q=lm][k=ks*32+lg*8+e]; B = sVt (XOR-granule layout)
    __builtin_amdgcn_s_setprio(1);
#pragma unroll
    for (int ks = 0; ks < 4; ++ks) {
      sx8 ap = *(const sx8*)&pw[pwb + (((ks << 4) + (lg << 2)) ^ wswz)];
      const int vrow = ((ks >> 1) << 6);
      const int vgr = (((ks & 1) << 2) + lg) ^ (lm & 7);
#pragma unroll
      for (int ot = 0; ot < 4; ++ot) {
        sx8 bv = *(const sx8*)&sVt[(vrow + (ot << 4) + lm) * 64 + (vgr << 3)];
        o[ot] = __builtin_amdgcn_mfma_f32_16x16x32_bf16(ap, bv, o[ot], 0, 0, 0);
      }
    }
    __builtin_amdgcn_s_setprio(0);
  }

  float inv = (lsum > 0.f) ? 1.f / lsum : 0.f;
#pragma unroll
  for (int r = 0; r < 4; ++r) {
    float ir = __shfl(inv, aslot + r);
#pragma unroll
    for (int ot = 0; ot < 4; ++ot) {
      const int rowg = q0 + (w << 4) + (lg << 2) + r;
      const int col = hoff + (ot << 4) + lm;
      ctx[((size_t)rowg << 10) + col] = f2b(o[ot][r] * ir);
    }
  }
}

// ---------------------------------------------------------------------------
__global__ __launch_bounds__(256)
void ln_dual(const u16* __restrict__ a, const void* __restrict__ res, long roff,
             const void* __restrict__ g1, const void* __restrict__ b1,
             const void* __restrict__ gf, const void* __restrict__ bf,
             u16* __restrict__ xo, u16* __restrict__ xlo, const int* f_p) {
  __shared__ float red[8];
  const bool f = (*f_p != 0);
  const int row = blockIdx.x, t = threadIdx.x;
  const int lane = t & 63, w = t >> 6;
  const size_t base = (size_t)row << 10;
  const int c = t << 2;

  ushx4 a4 = *(const ushx4*)(a + base + c);
  float rv[4];
  ld4f(res, roff + (long)base + c, f, rv);
  float v[4], s = 0.f, ss = 0.f;
#pragma unroll
  for (int j = 0; j < 4; ++j) { v[j] = b2f(a4[j]) + rv[j]; s += v[j]; ss += v[j] * v[j]; }
#pragma unroll
  for (int off = 32; off > 0; off >>= 1) { s += __shfl_xor(s, off); ss += __shfl_xor(ss, off); }
  if (lane == 0) { red[w] = s; red[4 + w] = ss; }
  __syncthreads();
  s = red[0] + red[1] + red[2] + red[3];
  ss = red[4] + red[5] + red[6] + red[7];
  float mu = s * (1.f / 1024.f);
  float rstd = rsqrtf(fmaxf(ss * (1.f / 1024.f) - mu * mu, 0.f) + 1e-5f);

  float g4[4], b4[4];
  ld4f(g1, c, f, g4); ld4f(b1, c, f, b4);
  float x[4], s2 = 0.f, ss2 = 0.f;
  ushx4 xo4;
#pragma unroll
  for (int j = 0; j < 4; ++j) {
    x[j] = (v[j] - mu) * rstd * g4[j] + b4[j];
    xo4[j] = f2b(x[j]);
    s2 += x[j]; ss2 += x[j] * x[j];
  }
  *(ushx4*)(xo + base + c) = xo4;
#pragma unroll
  for (int off = 32; off > 0; off >>= 1) { s2 += __shfl_xor(s2, off); ss2 += __shfl_xor(ss2, off); }
  __syncthreads();
  if (lane == 0) { red[w] = s2; red[4 + w] = ss2; }
  __syncthreads();
  s2 = red[0] + red[1] + red[2] + red[3];
  ss2 = red[4] + red[5] + red[6] + red[7];
  float mu2 = s2 * (1.f / 1024.f);
  float rstd2 = rsqrtf(fmaxf(ss2 * (1.f / 1024.f) - mu2 * mu2, 0.f) + 1e-5f);

  ld4f(gf, c, f, g4); ld4f(bf, c, f, b4);
  ushx4 xl4;
#pragma unroll
  for (int j = 0; j < 4; ++j)
    xl4[j] = f2b((x[j] - mu2) * rstd2 * g4[j] + b4[j]);
  *(ushx4*)(xlo + base + c) = xl4;
}

// ---------------------------------------------------------------------------
__global__ __launch_bounds__(256)
void ln_final(const u16* __restrict__ a, const u16* __restrict__ resx,
              const void* __restrict__ g, const void* __restrict__ bb,
              void* __restrict__ out, long ooff, const int* f_p) {
  __shared__ float red[8];
  const bool f = (*f_p != 0);
  const int row = blockIdx.x, t = threadIdx.x;
  const int lane = t & 63, w = t >> 6;
  const size_t base = (size_t)row << 10;
  const int c = t << 2;

  ushx4 a4 = *(const ushx4*)(a + base + c);
  ushx4 r4 = *(const ushx4*)(resx + base + c);
  float v[4], s = 0.f, ss = 0.f;
#pragma unroll
  for (int j = 0; j < 4; ++j) { v[j] = b2f(a4[j]) + b2f(r4[j]); s += v[j]; ss += v[j] * v[j]; }
#pragma unroll
  for (int off = 32; off > 0; off >>= 1) { s += __shfl_xor(s, off); ss += __shfl_xor(ss, off); }
  if (lane == 0) { red[w] = s; red[4 + w] = ss; }
  __syncthreads();
  s = red[0] + red[1] + red[2] + red[3];
  ss = red[4] + red[5] + red[6] + red[7];
  float mu = s * (1.f / 1024.f);
  float rstd = rsqrtf(fmaxf(ss * (1.f / 1024.f) - mu * mu, 0.f) + 1e-5f);

  float g4[4], b4[4];
  ld4f(g, c, f, g4); ld4f(bb, c, f, b4);
  if (f) {
    fx4 o4;
#pragma unroll
    for (int j = 0; j < 4; ++j) o4[j] = (v[j] - mu) * rstd * g4[j] + b4[j];
    *(fx4*)((float*)out + ooff + base + c) = o4;
  } else {
    ushx4 o4;
#pragma unroll
    for (int j = 0; j < 4; ++j) o4[j] = f2b((v[j] - mu) * rstd * g4[j] + b4[j]);
    *(ushx4*)((u16*)out + ooff + base + c) = o4;
  }
}

// ---------------------------------------------------------------------------
extern "C" void kernel_launch(void* const* d_in, const int* in_sizes, int n_in,
                              void* d_out, int out_size, void* d_ws, size_t ws_size,
                              hipStream_t stream) {
  (void)in_sizes; (void)n_in; (void)out_size;
  const void* query = d_in[0];
  const void* keyi  = d_in[1];
  const void* value = d_in[2];
  const int*  mask  = (const int*)d_in[3];
  const void* Wq = d_in[4];
  const void* Wk = d_in[5];
  const void* Wv = d_in[6];
  const void* Wo = d_in[7];
  const void* bo = d_in[8];
  const void* g1 = d_in[9];
  const void* b1 = d_in[10];
  const void* g2 = d_in[11];
  const void* b2 = d_in[12];
  const void* gff = d_in[13];
  const void* bff = d_in[14];
  const void* W1 = d_in[15];
  const void* bf1 = d_in[16];
  const void* W2 = d_in[17];
  const void* bf2 = d_in[18];

  char* p = (char*)d_ws;
  int* flags = (int*)p;
  const int* F = flags;
  const int* Z = flags + 1;
  const int* M = flags + 2;
  dim3 blk(256);

  // footprint(CH) = 4096 + 24MiB (packed weights) + 7*CH*2048 bytes
  const size_t FIXED = 4096 + ((size_t)24 << 20);
  const size_t needC = FIXED + (size_t)8192 * 14336;   // ~142.6 MB
  const size_t needA = FIXED + (size_t)4096 * 14336;   // ~80.0 MB
  const size_t needB = FIXED + (size_t)2048 * 14336;   // ~52.0 MB

  if (ws_size >= needB) {
    // ------------------------- NEW PATH -------------------------
    const int CH = (ws_size >= needC) ? 8192 : (ws_size >= needA) ? 4096 : 2048;
    const int nch = 8192 / CH;

    u16* Wqkv  = (u16*)(p + 4096);                       // [3*1024,1024]
    u16* Wo_bf = Wqkv + (size_t)3 * DM * DM;             // [1024,1024]
    u16* W1T   = Wo_bf + (size_t)DM * DM;                // [4096,1024]
    u16* W2T   = W1T + (size_t)DFF * DM;                 // [1024,4096]
    u16* D0    = W2T + (size_t)DM * DFF;                 // in_bf / h
    u16* D1    = D0 + (size_t)3 * CH * DM;               // qkv / ao,x,xln
    u16* D2    = D1 + (size_t)3 * CH * DM;               // ctx / ff
    u16* qb = D0;
    u16* qkv = D1;
    u16* ao = D1, *x = D1 + (size_t)CH * DM, *xln = D1 + (size_t)2 * CH * DM;
    u16* h = D0;                                         // CH*4096 elems
    u16* ctx = D2, *ff = D2;

    detect_kernel<<<1, 64, 0, stream>>>(query, flags);
    mask_scan<<<dim3(8192), blk, 0, stream>>>(mask, flags);
    pack_w<<<dim3(2048), blk, 0, stream>>>(Wq, Wk, Wv, Wo, Wqkv, Wo_bf, F);
    transpose_any<<<dim3(DFF / 64, DM / 64), blk, 0, stream>>>(W1, W1T, DM, DFF, F);
    transpose_any<<<dim3(DM / 64, DFF / 64), blk, 0, stream>>>(W2, W2T, DFF, DM, F);

    for (int c = 0; c < nch; ++c) {
      const long off = (long)c * CH * DM;
      const long n = (long)CH * DM;
      conv_bf3<<<dim3((int)(n >> 11), 3), blk, 0, stream>>>(query, keyi, value, off, qb, n, F);

      // q/k/v projections co-dispatched: z in {0,1,2}
      gemm_bb<false, false, false><<<dim3((CH / 128) * 8, 3), blk, 0, stream>>>(
          qb, (long)CH * DM, Wqkv, (long)DM * DM, nullptr,
          qkv, 1024L, CH, DM, DM, 3072, Z);

      const int bpc = CH / SEQ, b0 = c * bpc;
      attn_kernel<<<dim3(512, bpc), blk, 0, stream>>>(
          qkv, qkv + 1024, qkv + 2048, 3072,
          mask + (size_t)b0 * SEQ * SEQ, ctx, M);

      gemm_bb<false, true, true><<<dim3((CH / 128) * 8, 1), blk, 0, stream>>>(
          ctx, 0, Wo_bf, 0, bo, ao, 0, CH, DM, DM, DM, F);

      ln_dual<<<dim3(CH), blk, 0, stream>>>(ao, query, off, g1, b1, gff, bff, x, xln, F);

      gemm_bb<true, true, false><<<dim3((CH / 128) * 32, 1), blk, 0, stream>>>(
          xln, 0, W1T, 0, bf1, h, 0, CH, DFF, DM, DFF, F);
      gemm_bb<false, true, true><<<dim3((CH / 128) * 8, 1), blk, 0, stream>>>(
          h, 0, W2T, 0, bf2, ff, 0, CH, DM, DFF, DM, F);

      ln_final<<<dim3(CH), blk, 0, stream>>>(ff, x, g2, b2, d_out, off, F);
    }
  } else {
    // ------------------------- LEGACY PATH (round-3 proven) -------------------------
    const int CH = 2048, FH = 1024;
    const int nch = 8192 / CH;
    const size_t h0 = 4096;
    u16* W1T = (u16*)(p + h0);
    u16* W2T = W1T + (size_t)DFF * DM;
    u16* hb  = (u16*)(p + h0 + ((size_t)16 << 20));
    const size_t HB = (size_t)FH * DFF * 2;
    u16* r0 = (u16*)(p + h0 + ((size_t)16 << 20) + HB);
    const size_t CE = (size_t)CH * DM;
    u16* qp = r0;
    u16* kp = qp + CE;
    u16* vp = kp + CE;
    u16* ctxb = vp + CE;
    u16* x = qp; u16* xln = kp; u16* ao = vp; u16* ff = ctxb;

    detect_kernel<<<1, 64, 0, stream>>>(query, flags);
    mask_scan<<<dim3(8192), blk, 0, stream>>>(mask, flags);
    transpose_any<<<dim3(DFF / 64, DM / 64), blk, 0, stream>>>(W1, W1T, DM, DFF, F);
    transpose_any<<<dim3(DM / 64, DFF / 64), blk, 0, stream>>>(W2, W2T, DFF, DM, F);

    for (int c = 0; c < nch; ++c) {
      const long off = (long)c * CH * DM;
      dim3 gq((CH / 128) * (DM / 128));

      gemm_nt<false, false><<<gq, blk, 0, stream>>>(query, off, Wq, Wq, qp, CH, DM, DM, F, F, Z);
      gemm_nt<false, false><<<gq, blk, 0, stream>>>(keyi,  off, Wk, Wk, kp, CH, DM, DM, F, F, Z);
      gemm_nt<false, false><<<gq, blk, 0, stream>>>(value, off, Wv, Wv, vp, CH, DM, DM, F, F, Z);

      const int bpc = CH / SEQ, b0 = c * bpc;
      for (int bl = 0; bl < bpc; ++bl) {
        const size_t lo = (size_t)bl * SEQ * DM;
        attn_kernel<<<dim3(512, 1), blk, 0, stream>>>(
            qp + lo, kp + lo, vp + lo, 1024,
            mask + (size_t)(b0 + bl) * SEQ * SEQ, ctxb + lo, M);
      }

      gemm_nt<false, true><<<gq, blk, 0, stream>>>(ctxb, 0, Wo, bo, ao, CH, DM, DM, Z, F, F);

      ln_dual<<<dim3(CH), blk, 0, stream>>>(ao, query, off, g1, b1, gff, bff, x, xln, F);

      for (int qs = 0; qs < CH / FH; ++qs) {
        const long so = (long)qs * FH * DM;
        gemm_nt<true, true><<<dim3((FH / 128) * (DFF / 128)), blk, 0, stream>>>(
            xln + so, 0, W1T, bf1, hb, FH, DFF, DM, Z, Z, F);
        gemm_nt<false, true><<<dim3((FH / 128) * (DM / 128)), blk, 0, stream>>>(
            hb, 0, W2T, bf2, ff + so, FH, DM, DFF, Z, Z, F);
      }

      ln_final<<<dim3(CH), blk, 0, stream>>>(ff, x, g2, b2, d_out, off, F);
    }
  }
}